// Round 12
// baseline (343.700 us; speedup 1.0000x reference)
//
#include <hip/hip_runtime.h>
#include <hip/hip_bf16.h>

#define B_   4
#define N_   4096
#define HSZ  1024
#define H_   16
#define D_   64
#define NB_  64
#define R_   3
#define M_   (B_*N_)          // 16384 rows
#define NEGV (-1e4f)
#define LOG2E 1.4426950408889634f

typedef float f32x4 __attribute__((ext_vector_type(4)));
typedef short s16x8 __attribute__((ext_vector_type(8)));
typedef __bf16 b16x8 __attribute__((ext_vector_type(8)));

__device__ __forceinline__ f32x4 mfma16(s16x8 a, s16x8 b, f32x4 c) {
  return __builtin_amdgcn_mfma_f32_16x16x32_bf16(
      __builtin_bit_cast(b16x8, a), __builtin_bit_cast(b16x8, b), c, 0, 0, 0);
}

__device__ __forceinline__ short f2b(float x) {
  __hip_bfloat16 h = __float2bfloat16(x);
  return (short)__builtin_bit_cast(unsigned short, h);
}

__device__ __forceinline__ unsigned pack2(float a, float b) {
  return (unsigned)(unsigned short)f2b(a) |
         ((unsigned)(unsigned short)f2b(b) << 16);
}

// async global->LDS, 16B per lane; LDS dest = wave-uniform base + lane*16
__device__ __forceinline__ void gl_lds16(const short* g, short* l) {
  __builtin_amdgcn_global_load_lds(
      (const __attribute__((address_space(1))) unsigned int*)g,
      (__attribute__((address_space(3))) unsigned int*)l, 16, 0, 0);
}

// ---------------- fused conversions: xs->bf16 + weight transpose ----------
__global__ __launch_bounds__(256) void k_prep(const float* __restrict__ in,
                                              short* __restrict__ out,
                                              const float* __restrict__ Wq,
                                              const float* __restrict__ Wk,
                                              const float* __restrict__ Wv,
                                              const float* __restrict__ Wo,
                                              short* __restrict__ wt) {
  const int tid = threadIdx.x;
  if (blockIdx.x < 8192) {
    size_t i = ((size_t)blockIdx.x * 256 + tid) * 8;
    float4 a = *(const float4*)&in[i];
    float4 b = *(const float4*)&in[i + 4];
    s16x8 o;
    o[0] = f2b(a.x); o[1] = f2b(a.y); o[2] = f2b(a.z); o[3] = f2b(a.w);
    o[4] = f2b(b.x); o[5] = f2b(b.y); o[6] = f2b(b.z); o[7] = f2b(b.w);
    *(s16x8*)&out[i] = o;
    return;
  }
  const int bid = blockIdx.x - 8192;            // 0..1023
  const int z = bid >> 8;
  const int rest = bid & 255;
  const int tk = (rest >> 4) * 64, tn = (rest & 15) * 64;
  const float* src = (z == 0) ? Wq : (z == 1) ? Wk : (z == 2) ? Wv : Wo;
  short* dst = wt + (size_t)z * HSZ * HSZ;
  __shared__ __align__(16) float t[64][68];
#pragma unroll
  for (int r = 0; r < 4; ++r) {
    int c = tid + r * 256;
    int row = c >> 4, seg = c & 15;
    *(float4*)&t[row][seg * 4] =
        *(const float4*)&src[(size_t)(tk + row) * HSZ + tn + seg * 4];
  }
  __syncthreads();
#pragma unroll
  for (int r = 0; r < 2; ++r) {
    int c = tid + r * 256;
    int row = c >> 3, seg = c & 7;
    s16x8 o;
#pragma unroll
    for (int u = 0; u < 8; ++u) o[u] = f2b(t[seg * 8 + u][row]);
    *(s16x8*)&dst[(size_t)(tn + row) * HSZ + tk + seg * 8] = o;
  }
}

// ---------------- GEMM core: counted-vmcnt dbuf K-loop ----------------
template <bool SWAP>
__device__ __forceinline__ void gemm_core(
    const short* __restrict__ A, const short* __restrict__ Bt, int tm, int tn,
    short (&a_lds)[2][128][64], short (&b_lds)[2][128][64],
    f32x4 (&acc)[4][4], int wave, int lane) {
  const int lq = lane & 15, g = lane >> 4;
  const int wm = (wave & 1) * 64, wn = (wave >> 1) * 64;
  const int srow = wave * 32 + (lane >> 3);
  const int scol = ((lane & 7) ^ ((lane >> 3) & 7)) * 8;

  auto STAGE = [&](int buf, int kt) {
#pragma unroll
    for (int u = 0; u < 4; ++u) {
      gl_lds16(&A[(size_t)(tm + srow + u * 8) * HSZ + kt + scol],
               &a_lds[buf][wave * 32 + u * 8][0]);
      gl_lds16(&Bt[(size_t)(tn + srow + u * 8) * HSZ + kt + scol],
               &b_lds[buf][wave * 32 + u * 8][0]);
    }
  };

  const int sw = (lq & 7) << 3;
  auto COMPUTE = [&](int buf) {
#pragma unroll
    for (int kk = 0; kk < 2; ++kk) {
      const int ko = (kk * 32 + g * 8) ^ sw;
      s16x8 af[4], bf[4];
#pragma unroll
      for (int i = 0; i < 4; ++i)
        af[i] = *(const s16x8*)&a_lds[buf][wm + i * 16 + lq][ko];
#pragma unroll
      for (int j = 0; j < 4; ++j)
        bf[j] = *(const s16x8*)&b_lds[buf][wn + j * 16 + lq][ko];
#pragma unroll
      for (int i = 0; i < 4; ++i)
#pragma unroll
        for (int j = 0; j < 4; ++j)
          acc[i][j] = SWAP ? mfma16(bf[j], af[i], acc[i][j])
                           : mfma16(af[i], bf[j], acc[i][j]);
    }
  };

  STAGE(0, 0);
  STAGE(1, 64);
  int cur = 0;
  for (int s2 = 0; s2 < 14; ++s2) {
    asm volatile("s_waitcnt vmcnt(8)" ::: "memory");
    __builtin_amdgcn_s_barrier();
    COMPUTE(cur);
    __builtin_amdgcn_s_barrier();
    STAGE(cur, (s2 + 2) * 64);
    cur ^= 1;
  }
  asm volatile("s_waitcnt vmcnt(8)" ::: "memory");
  __builtin_amdgcn_s_barrier();
  COMPUTE(cur);
  cur ^= 1;
  asm volatile("s_waitcnt vmcnt(0)" ::: "memory");
  __builtin_amdgcn_s_barrier();
  COMPUTE(cur);
}

// QKV projection, one launch, z interleaved per-XCD so the three z-slices of
// the same A-panel are co-resident on one XCD (A fetched from HBM once).
// grid 3072: xcd=orig&7, r=orig>>3; tm_local=r/24, z=(r%24)/8, tn=r%8.
__global__ __launch_bounds__(256) void k_qkv(
    const short* __restrict__ A, const short* __restrict__ WT,
    const float* __restrict__ bq, const float* __restrict__ bk,
    const float* __restrict__ bv, short* __restrict__ oq,
    short* __restrict__ ok, short* __restrict__ ovt) {
  const int orig = blockIdx.x;                 // 0..3071
  const int xcd = orig & 7, r = orig >> 3;     // r: 0..383
  const int tml = r / 24, rem = r % 24;
  const int z = rem >> 3, tnl = rem & 7;
  const int tm = (xcd * 16 + tml) * 128, tn = tnl * 128;
  const short* Bt = WT + (size_t)z * HSZ * HSZ;

  __shared__ __align__(16) short a_lds[2][128][64];
  __shared__ __align__(16) short b_lds[2][128][64];

  const int tid = threadIdx.x, lane = tid & 63, wave = tid >> 6;
  const int lq = lane & 15, g = lane >> 4;
  const int wm = (wave & 1) * 64, wn = (wave >> 1) * 64;

  f32x4 acc[4][4] = {};

  if (z == 2) {
    gemm_core<false>(A, Bt, tm, tn, a_lds, b_lds, acc, wave, lane);
    // unswapped: lane holds 4 consecutive tokens (rows) for one d-col
#pragma unroll
    for (int j = 0; j < 4; ++j) {
      const int col = tn + wn + j * 16 + lq;
      const int hh = col >> 6, dd = col & 63;
      const float bi = bv[col];
#pragma unroll
      for (int i = 0; i < 4; ++i) {
        const int nrow = tm + wm + i * 16 + g * 4;
        const int bb = nrow >> 12, nn = nrow & (N_ - 1);
        uint2 w;
        w.x = pack2(acc[i][j][0] + bi, acc[i][j][1] + bi);
        w.y = pack2(acc[i][j][2] + bi, acc[i][j][3] + bi);
        *(uint2*)&ovt[(((size_t)bb * H_ + hh) * D_ + dd) * N_ + nn] = w;
      }
    }
  } else {
    gemm_core<true>(A, Bt, tm, tn, a_lds, b_lds, acc, wave, lane);
    const float* bias = z ? bk : bq;
    short* outb = z ? ok : oq;
    const float alpha = z ? 1.0f : 0.125f * LOG2E;
    // swapped: lane holds 4 consecutive N-cols for one M-row
#pragma unroll
    for (int i = 0; i < 4; ++i) {
      const int row = tm + wm + i * 16 + lq;
#pragma unroll
      for (int j = 0; j < 4; ++j) {
        const int colb = tn + wn + j * 16 + g * 4;
        const float4 bi = *(const float4*)&bias[colb];
        const int bb = row >> 12, nn = row & (N_ - 1);
        const int hh = colb >> 6, dd = colb & 63;
        uint2 w;
        w.x = pack2((acc[i][j][0] + bi.x) * alpha,
                    (acc[i][j][1] + bi.y) * alpha);
        w.y = pack2((acc[i][j][2] + bi.z) * alpha,
                    (acc[i][j][3] + bi.w) * alpha);
        *(uint2*)&outb[(((size_t)bb * H_ + hh) * N_ + nn) * D_ + dd] = w;
      }
    }
  }
}

// Output projection: y = ctx @ Wo^T + bo + xs (f32)
__global__ __launch_bounds__(256) void k_out(
    const short* __restrict__ A, const short* __restrict__ WT,
    const float* __restrict__ bo, const float* __restrict__ xs,
    float* __restrict__ yout) {
  const short* Bt = WT + (size_t)3 * HSZ * HSZ;

  __shared__ __align__(16) short a_lds[2][128][64];
  __shared__ __align__(16) short b_lds[2][128][64];

  const int tid = threadIdx.x, lane = tid & 63, wave = tid >> 6;
  const int lq = lane & 15, g = lane >> 4;
  const int wm = (wave & 1) * 64, wn = (wave >> 1) * 64;
  const int orig = blockIdx.x;
  const int swg = (orig & 7) * 128 + (orig >> 3);
  const int tm = (swg >> 3) * 128, tn = (swg & 7) * 128;

  f32x4 acc[4][4] = {};
  gemm_core<true>(A, Bt, tm, tn, a_lds, b_lds, acc, wave, lane);

#pragma unroll
  for (int i = 0; i < 4; ++i) {
    const int row = tm + wm + i * 16 + lq;
#pragma unroll
    for (int j = 0; j < 4; ++j) {
      const int colb = tn + wn + j * 16 + g * 4;
      const float4 bi = *(const float4*)&bo[colb];
      const size_t idx = (size_t)row * HSZ + colb;
      const float4 xv = *(const float4*)&xs[idx];
      float4 yv;
      yv.x = acc[i][j][0] + bi.x + xv.x;
      yv.y = acc[i][j][1] + bi.y + xv.y;
      yv.z = acc[i][j][2] + bi.z + xv.z;
      yv.w = acc[i][j][3] + bi.w + xv.w;
      *(float4*)&yout[idx] = yv;
    }
  }
}

// ---------------- BigBird block-sparse attention ----------------
// R11 structure: denominator on the MFMA pipe (ones-column), bias as MFMA
// C-in (precomputed for all 8 slots), XOR-swizzled K/V^T LDS, XCD-grouped
// grid, uniform-shift softmax (no per-tile max tracking).
// slots 0..61 = middle qb=1..62; 62..77 = edge chunks (qb 0/63, 8 blocks ea).
__global__ __launch_bounds__(256) void k_attn(
    const short* __restrict__ Q, const short* __restrict__ K,
    const short* __restrict__ VT, const int* __restrict__ mask,
    const int* __restrict__ rnd, short* __restrict__ ctx,
    float* __restrict__ pO, float* __restrict__ pm, float* __restrict__ pl) {
  const int orig = blockIdx.x;                 // 0..4991
  const int swg = (orig & 7) * 624 + (orig >> 3);
  const int s = swg % 78;
  const int bh_i = swg / 78;                   // 0..63
  const int h = bh_i & 15, b = bh_i >> 4;
  const int tid = threadIdx.x, lane = tid & 63, wave = tid >> 6;
  const int g = lane >> 4, lq = lane & 15;

  __shared__ __align__(16) short k_lds[64][64];
  __shared__ __align__(16) short vt_lds[64][64];
  __shared__ __align__(16) short p_lds[4][16][72];
  __shared__ __align__(16) float bias_s[8][64];
  __shared__ int list_s[8];
  __shared__ int Ls;

  const bool mid = (s < 62);
  const int qb = mid ? (s + 1) : (((s - 62) >> 3) ? (NB_ - 1) : 0);

  if (tid == 0) {
    int L;
    if (!mid) {
      int chunk = (s - 62) & 7;
#pragma unroll
      for (int i = 0; i < 8; ++i) list_s[i] = chunk * 8 + i;
      L = 8;
    } else {
      const int* rp = rnd + ((size_t)h * (NB_ - 2) + (qb - 1)) * R_;
      int n;
      if (qb == 1) {
        list_s[0] = 0; list_s[1] = 1; list_s[2] = 2; list_s[3] = NB_ - 1; n = 4;
      } else if (qb == NB_ - 2) {
        list_s[0] = NB_ - 3; list_s[1] = NB_ - 2; list_s[2] = NB_ - 1;
        list_s[3] = 0; n = 4;
      } else {
        list_s[0] = qb - 1; list_s[1] = qb; list_s[2] = qb + 1;
        list_s[3] = 0; list_s[4] = NB_ - 1; n = 5;
      }
      for (int j = 0; j < R_; ++j) list_s[n + j] = rp[j];
      L = n + R_;
      for (int i = L; i < 8; ++i) list_s[i] = 0;   // keep indices safe
    }
    Ls = L;
  }

  const size_t bh = (size_t)b * H_ + h;
  const size_t qrow = bh * N_ + (size_t)qb * 64 + wave * 16 + lq;
  s16x8 qf0 = *(const s16x8*)&Q[qrow * D_ + g * 8];
  s16x8 qf1 = *(const s16x8*)&Q[qrow * D_ + 32 + g * 8];

  __syncthreads();
  const int L = Ls;

  const int r0 = tid >> 3, sg = tid & 7;     // r0: 0..31, two rows each
  const int csl = (sg ^ (r0 & 7)) * 8;       // swizzled 16B slot (write side)
  const int sw = (lq & 7);                   // read-side row XOR key

  const short* Kb = K + bh * (size_t)N_ * D_;
  const short* Vb = VT + bh * (size_t)D_ * N_;
  const int* mb = mask + (size_t)b * N_;

  // precompute bias rows for all 8 list slots (ordered by in-loop barrier)
  for (int t = tid; t < 512; t += 256) {
    const int i = t >> 6, kk2 = t & 63;
    bias_s[i][kk2] =
        (1.0f - (float)mb[list_s[i] * 64 + kk2]) * (NEGV * LOG2E);
  }

  s16x8 kr0, kr1, vr0, vr1;
  {
    const int kb = list_s[0];
    const short* kp = Kb + (size_t)kb * 64 * D_;
    const short* vp = Vb + (size_t)kb * 64;
    kr0 = *(const s16x8*)&kp[(size_t)r0 * D_ + sg * 8];
    kr1 = *(const s16x8*)&kp[(size_t)(r0 + 32) * D_ + sg * 8];
    vr0 = *(const s16x8*)&vp[(size_t)r0 * N_ + sg * 8];
    vr1 = *(const s16x8*)&vp[(size_t)(r0 + 32) * N_ + sg * 8];
  }

  s16x8 ones;
#pragma unroll
  for (int u = 0; u < 8; ++u) ones[u] = (short)0x3F80;  // bf16 1.0

  f32x4 o[4] = {};
  f32x4 osum = {};
  float mshift = 0.0f;

  for (int it = 0; it < L; ++it) {
    // commit staged tile to LDS (XOR-swizzled), issue next tile's loads
    *(s16x8*)&k_lds[r0][csl] = kr0;
    *(s16x8*)&k_lds[r0 + 32][csl] = kr1;
    *(s16x8*)&vt_lds[r0][csl] = vr0;
    *(s16x8*)&vt_lds[r0 + 32][csl] = vr1;
    if (it + 1 < L) {
      const int kb = list_s[it + 1];
      const short* kp = Kb + (size_t)kb * 64 * D_;
      const short* vp = Vb + (size_t)kb * 64;
      kr0 = *(const s16x8*)&kp[(size_t)r0 * D_ + sg * 8];
      kr1 = *(const s16x8*)&kp[(size_t)(r0 + 32) * D_ + sg * 8];
      vr0 = *(const s16x8*)&vp[(size_t)r0 * N_ + sg * 8];
      vr1 = *(const s16x8*)&vp[(size_t)(r0 + 32) * N_ + sg * 8];
    }
    __syncthreads();

    // S^T = K @ Q^T, bias preloaded as MFMA C-in (rows=keys, cols=queries)
    f32x4 st[4];
#pragma unroll
    for (int f = 0; f < 4; ++f) {
      f32x4 a0 = *(const f32x4*)&bias_s[it][f * 16 + g * 4];
      s16x8 af0 = *(const s16x8*)&k_lds[f * 16 + lq][(g ^ sw) * 8];
      s16x8 af1 = *(const s16x8*)&k_lds[f * 16 + lq][((4 + g) ^ sw) * 8];
      a0 = mfma16(af0, qf0, a0);
      a0 = mfma16(af1, qf1, a0);
      st[f] = a0;
    }

    // exp2 (uniform-shift online softmax; fast path while mshift==0)
    if (mshift == 0.0f) {
#pragma unroll
      for (int f = 0; f < 4; ++f)
#pragma unroll
        for (int e = 0; e < 4; ++e) st[f][e] = exp2f(st[f][e]);
    } else {
#pragma unroll
      for (int f = 0; f < 4; ++f)
#pragma unroll
        for (int e = 0; e < 4; ++e) st[f][e] = exp2f(st[f][e] - mshift);
    }

    // P rows to per-wave LDS (row = query lq, cols = keys)
#pragma unroll
    for (int f = 0; f < 4; ++f) {
      uint2 w = make_uint2(pack2(st[f][0], st[f][1]),
                           pack2(st[f][2], st[f][3]));
      *(uint2*)&p_lds[wave][lq][f * 16 + g * 4] = w;
    }

    // O += P @ V ; denominator via ones-column on the MFMA pipe
#pragma unroll
    for (int kk = 0; kk < 2; ++kk) {
      s16x8 pa = *(const s16x8*)&p_lds[wave][lq][kk * 32 + g * 8];
#pragma unroll
      for (int j = 0; j < 4; ++j) {
        s16x8 bv =
            *(const s16x8*)&vt_lds[j * 16 + lq][((kk * 4 + g) ^ sw) * 8];
        o[j] = mfma16(pa, bv, o[j]);
      }
      osum = mfma16(pa, ones, osum);
    }

    // overflow guard: uniform shift (never fires on typical data)
    float om = fmaxf(fmaxf(osum[0], osum[1]), fmaxf(osum[2], osum[3]));
    if (__any(om > 16777216.0f)) {
#pragma unroll
      for (int j = 0; j < 4; ++j) o[j] *= 5.9604645e-08f;  // 2^-24
      osum *= 5.9604645e-08f;
      mshift += 24.0f;
    }
    __syncthreads();
  }

  if (mid) {
    float rs[4];
#pragma unroll
    for (int e = 0; e < 4; ++e)
      rs[e] = (float)mb[qb * 64 + wave * 16 + g * 4 + e] /
              fmaxf(osum[e], 1e-30f);
#pragma unroll
    for (int j = 0; j < 4; ++j) {
      k_lds[wave * 16 + g * 4 + 0][j * 16 + lq] = f2b(o[j][0] * rs[0]);
      k_lds[wave * 16 + g * 4 + 1][j * 16 + lq] = f2b(o[j][1] * rs[1]);
      k_lds[wave * 16 + g * 4 + 2][j * 16 + lq] = f2b(o[j][2] * rs[2]);
      k_lds[wave * 16 + g * 4 + 3][j * 16 + lq] = f2b(o[j][3] * rs[3]);
    }
    __syncthreads();
#pragma unroll
    for (int pp = 0; pp < 2; ++pp) {
      int c = tid + pp * 256;
      int row = c >> 3, seg = c & 7;
      *(s16x8*)&ctx[((size_t)b * N_ + qb * 64 + row) * HSZ + h * D_ + seg * 8] =
          *(const s16x8*)&k_lds[row][seg * 8];
    }
  } else {
    const int e2 = s - 62;
    const int qsel = e2 >> 3, chunk = e2 & 7;
    const size_t eidx = (bh * 2 + qsel) * 8 + chunk;
    float* po = pO + eidx * 4096;
#pragma unroll
    for (int j = 0; j < 4; ++j)
#pragma unroll
      for (int e = 0; e < 4; ++e)
        po[(wave * 16 + g * 4 + e) * 64 + j * 16 + lq] = o[j][e];
    if (lq == 0) {
#pragma unroll
      for (int e = 0; e < 4; ++e) {
        pm[eidx * 64 + wave * 16 + g * 4 + e] = mshift;
        pl[eidx * 64 + wave * 16 + g * 4 + e] = osum[e];
      }
    }
  }
}

// ---------------- combine edge partials (log2-domain shifts) ----------------
__global__ __launch_bounds__(256) void k_comb(
    const float* __restrict__ pO, const float* __restrict__ pm,
    const float* __restrict__ pl, const int* __restrict__ mask,
    short* __restrict__ ctx) {
  const int qsel = blockIdx.x, h = blockIdx.y, b = blockIdx.z;
  const int qb = qsel ? NB_ - 1 : 0;
  const int tid = threadIdx.x;
  const int q = tid >> 2, dq = tid & 3;
  const size_t base = (((size_t)b * H_ + h) * 2 + qsel) * 8;

  float mv[8];
  float M = -INFINITY;
#pragma unroll
  for (int i = 0; i < 8; ++i) {
    mv[i] = pm[(base + i) * 64 + q];
    M = fmaxf(M, mv[i]);
  }
  float Lsum = 0.0f;
#pragma unroll
  for (int i = 0; i < 8; ++i) {
    float w = exp2f(mv[i] - M);
    mv[i] = w;
    Lsum += pl[(base + i) * 64 + q] * w;
  }
  f32x4 acc[4] = {};
#pragma unroll
  for (int i = 0; i < 8; ++i) {
    const float* p = pO + (base + i) * 4096 + q * 64 + dq * 16;
    float w = mv[i];
#pragma unroll
    for (int u = 0; u < 4; ++u) {
      f32x4 v = *(const f32x4*)&p[u * 4];
      acc[u] += v * w;
    }
  }
  float sc = (float)mask[(size_t)b * N_ + qb * 64 + q] / fmaxf(Lsum, 1e-30f);
  s16x8 out0, out1;
#pragma unroll
  for (int u = 0; u < 8; ++u) {
    out0[u] = f2b(acc[u >> 2][u & 3] * sc);
    out1[u] = f2b(acc[2 + (u >> 2)][u & 3] * sc);
  }
  short* dst = &ctx[((size_t)b * N_ + qb * 64 + q) * HSZ + h * D_ + dq * 16];
  *(s16x8*)dst = out0;
  *(s16x8*)(dst + 8) = out1;
}

// ---------------- LayerNorm (in place on y) ----------------
__global__ __launch_bounds__(256) void k_ln(float* __restrict__ y,
                                            const float* __restrict__ gamma,
                                            const float* __restrict__ beta) {
  const int row = blockIdx.x, tid = threadIdx.x, lane = tid & 63,
            wave = tid >> 6;
  __shared__ float s_sum[4], s_sq[4];
  float4 v = *(const float4*)&y[(size_t)row * HSZ + tid * 4];
  float s = v.x + v.y + v.z + v.w;
  float q = v.x * v.x + v.y * v.y + v.z * v.z + v.w * v.w;
#pragma unroll
  for (int m = 1; m <= 32; m <<= 1) {
    s += __shfl_xor(s, m);
    q += __shfl_xor(q, m);
  }
  if (lane == 0) { s_sum[wave] = s; s_sq[wave] = q; }
  __syncthreads();
  float S = s_sum[0] + s_sum[1] + s_sum[2] + s_sum[3];
  float Qs = s_sq[0] + s_sq[1] + s_sq[2] + s_sq[3];
  float mu = S * (1.0f / HSZ);
  float var = Qs * (1.0f / HSZ) - mu * mu;
  float r = rsqrtf(var + 1e-12f);
  float4 g = *(const float4*)&gamma[tid * 4];
  float4 be = *(const float4*)&beta[tid * 4];
  float4 outv;
  outv.x = (v.x - mu) * r * g.x + be.x;
  outv.y = (v.y - mu) * r * g.y + be.y;
  outv.z = (v.z - mu) * r * g.z + be.z;
  outv.w = (v.w - mu) * r * g.w + be.w;
  *(float4*)&y[(size_t)row * HSZ + tid * 4] = outv;
}

// ---------------- launch ----------------
extern "C" void kernel_launch(void* const* d_in, const int* in_sizes, int n_in,
                              void* d_out, int out_size, void* d_ws,
                              size_t ws_size, hipStream_t stream) {
  const float* xs = (const float*)d_in[0];
  const int* mask = (const int*)d_in[1];
  const float* Wq = (const float*)d_in[2];
  const float* bq = (const float*)d_in[3];
  const float* Wk = (const float*)d_in[4];
  const float* bk = (const float*)d_in[5];
  const float* Wv = (const float*)d_in[6];
  const float* bv = (const float*)d_in[7];
  const float* Wo = (const float*)d_in[8];
  const float* bo = (const float*)d_in[9];
  const float* gamma = (const float*)d_in[10];
  const float* beta = (const float*)d_in[11];
  const int* rnd = (const int*)d_in[12];
  float* yout = (float*)d_out;

  char* ws = (char*)d_ws;
  const size_t SZ_XS = (size_t)M_ * HSZ * 2;       // 32 MB
  const size_t SZ_WT = (size_t)4 * HSZ * HSZ * 2;  // 8 MB
  short* xsb = (short*)ws;                         // also reused as ctx
  short* wt = (short*)(ws + SZ_XS);
  short* qbuf = (short*)(ws + SZ_XS + SZ_WT);
  short* kbuf = qbuf + (size_t)M_ * HSZ;
  short* vtb = kbuf + (size_t)M_ * HSZ;            // V^T (b,h,d,n)
  char* after = ws + SZ_XS + SZ_WT + 3 * SZ_XS;
  float* pO = (float*)(after + (1 << 20));         // 1024*4096 f32 = 16 MB
  float* pm = pO + (size_t)1024 * 4096;            // 256 KB
  float* pl = pm + (size_t)1024 * 64;              // 256 KB

  k_prep<<<9216, 256, 0, stream>>>(xs, xsb, Wq, Wk, Wv, Wo, wt);
  k_qkv<<<3072, 256, 0, stream>>>(xsb, wt, bq, bk, bv, qbuf, kbuf, vtb);
  k_attn<<<4992, 256, 0, stream>>>(qbuf, kbuf, vtb, mask, rnd, xsb, pO, pm,
                                   pl);
  k_comb<<<dim3(2, H_, B_), 256, 0, stream>>>(pO, pm, pl, mask, xsb);
  k_out<<<1024, 256, 0, stream>>>(xsb, wt, bo, xs, yout);
  k_ln<<<M_, 256, 0, stream>>>(yout, gamma, beta);
}

// Round 13
// 325.365 us; speedup vs baseline: 1.0564x; 1.0564x over previous
//
#include <hip/hip_runtime.h>
#include <hip/hip_bf16.h>

#define B_   4
#define N_   4096
#define HSZ  1024
#define H_   16
#define D_   64
#define NB_  64
#define R_   3
#define M_   (B_*N_)          // 16384 rows
#define NEGV (-1e4f)
#define LOG2E 1.4426950408889634f

typedef float f32x4 __attribute__((ext_vector_type(4)));
typedef short s16x8 __attribute__((ext_vector_type(8)));
typedef __bf16 b16x8 __attribute__((ext_vector_type(8)));

__device__ __forceinline__ f32x4 mfma16(s16x8 a, s16x8 b, f32x4 c) {
  return __builtin_amdgcn_mfma_f32_16x16x32_bf16(
      __builtin_bit_cast(b16x8, a), __builtin_bit_cast(b16x8, b), c, 0, 0, 0);
}

__device__ __forceinline__ short f2b(float x) {
  __hip_bfloat16 h = __float2bfloat16(x);
  return (short)__builtin_bit_cast(unsigned short, h);
}

__device__ __forceinline__ unsigned pack2(float a, float b) {
  return (unsigned)(unsigned short)f2b(a) |
         ((unsigned)(unsigned short)f2b(b) << 16);
}

// async global->LDS, 16B per lane; LDS dest = wave-uniform base + lane*16
__device__ __forceinline__ void gl_lds16(const short* g, short* l) {
  __builtin_amdgcn_global_load_lds(
      (const __attribute__((address_space(1))) unsigned int*)g,
      (__attribute__((address_space(3))) unsigned int*)l, 16, 0, 0);
}

// ---------------- fused conversions: xs->bf16 + weight transpose ----------
__global__ __launch_bounds__(256) void k_prep(const float* __restrict__ in,
                                              short* __restrict__ out,
                                              const float* __restrict__ Wq,
                                              const float* __restrict__ Wk,
                                              const float* __restrict__ Wv,
                                              const float* __restrict__ Wo,
                                              short* __restrict__ wt) {
  const int tid = threadIdx.x;
  if (blockIdx.x < 8192) {
    size_t i = ((size_t)blockIdx.x * 256 + tid) * 8;
    float4 a = *(const float4*)&in[i];
    float4 b = *(const float4*)&in[i + 4];
    s16x8 o;
    o[0] = f2b(a.x); o[1] = f2b(a.y); o[2] = f2b(a.z); o[3] = f2b(a.w);
    o[4] = f2b(b.x); o[5] = f2b(b.y); o[6] = f2b(b.z); o[7] = f2b(b.w);
    *(s16x8*)&out[i] = o;
    return;
  }
  const int bid = blockIdx.x - 8192;            // 0..1023
  const int z = bid >> 8;
  const int rest = bid & 255;
  const int tk = (rest >> 4) * 64, tn = (rest & 15) * 64;
  const float* src = (z == 0) ? Wq : (z == 1) ? Wk : (z == 2) ? Wv : Wo;
  short* dst = wt + (size_t)z * HSZ * HSZ;
  __shared__ __align__(16) float t[64][68];
#pragma unroll
  for (int r = 0; r < 4; ++r) {
    int c = tid + r * 256;
    int row = c >> 4, seg = c & 15;
    *(float4*)&t[row][seg * 4] =
        *(const float4*)&src[(size_t)(tk + row) * HSZ + tn + seg * 4];
  }
  __syncthreads();
#pragma unroll
  for (int r = 0; r < 2; ++r) {
    int c = tid + r * 256;
    int row = c >> 3, seg = c & 7;
    s16x8 o;
#pragma unroll
    for (int u = 0; u < 8; ++u) o[u] = f2b(t[seg * 8 + u][row]);
    *(s16x8*)&dst[(size_t)(tn + row) * HSZ + tk + seg * 8] = o;
  }
}

// ---------------- 256x256 8-phase GEMM core (T3+T4) ----------------
// 8 waves (2M x 4N), BK=64, 16 K-tiles, dbuf LDS, counted vmcnt (never 0
// in steady state). Per pair (t even in buf0, t+1 in buf1), 8 phases:
// P0: stage A(t+1)->buf1 | vmcnt(8) | bar | ldB(t)+ldA | 16 MFMA | bar
// P1: stage B(t+2)->buf0 | ldA | 16 MFMA | bar      (buf0.B freed at P0-bar)
// P2,P3: ldA | 16 MFMA | bar                        (A(t) freed at P3-bar)
// P4: stage A(t+2)->buf0 | vmcnt(8 / 0 last) | bar | ldB(t+1)+ldA | MFMA | bar
// P5: stage B(t+3)->buf1 | ldA | MFMA | bar         (buf1.B freed at P4-bar)
// P6,P7: ldA | MFMA | bar                           (A(t+1) freed at P7-bar)
template <bool SWAP>
__device__ __forceinline__ void gemm8_core(
    const short* __restrict__ A, const short* __restrict__ Bt, int tm, int tn,
    short (&a_lds)[2][256][64], short (&b_lds)[2][256][64],
    f32x4 (&acc)[8][4], int wave, int lane) {
  const int lq = lane & 15, g = lane >> 4;
  const int wm = wave >> 2, wn = wave & 3;
  const int sl8 = lane >> 3;
  const int sc = ((lane & 7) ^ sl8) * 8;   // pre-swizzled global 16B slot

  auto ST_A = [&](int buf, int kt, int h) {
#pragma unroll
    for (int u = 0; u < 2; ++u) {
      const int rbase = h * 128 + wave * 8 + u * 64;
      gl_lds16(&A[(size_t)(tm + rbase + sl8) * HSZ + kt * 64 + sc],
               &a_lds[buf][rbase][0]);
    }
  };
  auto ST_B = [&](int buf, int kt, int h) {
#pragma unroll
    for (int u = 0; u < 2; ++u) {
      const int rbase = h * 128 + wave * 8 + u * 64;
      gl_lds16(&Bt[(size_t)(tn + rbase + sl8) * HSZ + kt * 64 + sc],
               &b_lds[buf][rbase][0]);
    }
  };

  s16x8 bf[4][2];
  auto LOADB = [&](int buf) {
#pragma unroll
    for (int j = 0; j < 4; ++j) {
      const int row = wn * 64 + j * 16 + lq;
#pragma unroll
      for (int kk = 0; kk < 2; ++kk)
        bf[j][kk] =
            *(const s16x8*)&b_lds[buf][row][((kk * 4 + g) ^ (lq & 7)) * 8];
    }
  };
  auto PH = [&](int buf, int m0) {
    s16x8 af[2][2];
#pragma unroll
    for (int i = 0; i < 2; ++i) {
      const int row = wm * 128 + (m0 + i) * 16 + lq;
#pragma unroll
      for (int kk = 0; kk < 2; ++kk)
        af[i][kk] =
            *(const s16x8*)&a_lds[buf][row][((kk * 4 + g) ^ (lq & 7)) * 8];
    }
    __builtin_amdgcn_s_setprio(1);
#pragma unroll
    for (int i = 0; i < 2; ++i)
#pragma unroll
      for (int j = 0; j < 4; ++j)
#pragma unroll
        for (int kk = 0; kk < 2; ++kk)
          acc[m0 + i][j] = SWAP
                               ? mfma16(bf[j][kk], af[i][kk], acc[m0 + i][j])
                               : mfma16(af[i][kk], bf[j][kk], acc[m0 + i][j]);
    __builtin_amdgcn_s_setprio(0);
    __builtin_amdgcn_s_barrier();
  };

  // prologue: tile0 (A+B) + tile1 B  -> 12 loads/thread-pair outstanding
  ST_A(0, 0, 0); ST_A(0, 0, 1);
  ST_B(0, 0, 0); ST_B(0, 0, 1);
  ST_B(1, 1, 0); ST_B(1, 1, 1);

  for (int p = 0; p < 8; ++p) {
    const int t = 2 * p;
    // P0
    ST_A(1, t + 1, 0); ST_A(1, t + 1, 1);
    asm volatile("s_waitcnt vmcnt(8)" ::: "memory");
    __builtin_amdgcn_s_barrier();
    LOADB(0);
    PH(0, 0);
    // P1
    if (t + 2 < 16) { ST_B(0, t + 2, 0); ST_B(0, t + 2, 1); }
    PH(0, 2);
    // P2
    PH(0, 4);
    // P3
    PH(0, 6);
    // P4
    if (t + 2 < 16) { ST_A(0, t + 2, 0); ST_A(0, t + 2, 1); }
    if (p < 7) {
      asm volatile("s_waitcnt vmcnt(8)" ::: "memory");
    } else {
      asm volatile("s_waitcnt vmcnt(0)" ::: "memory");
    }
    __builtin_amdgcn_s_barrier();
    LOADB(1);
    PH(1, 0);
    // P5
    if (t + 3 < 16) { ST_B(1, t + 3, 0); ST_B(1, t + 3, 1); }
    PH(1, 2);
    // P6
    PH(1, 4);
    // P7
    PH(1, 6);
  }
}

// QKV projection: grid 768 (1D, XCD-grouped), 512 thr. z=0 Q (swapped,
// scaled), z=1 K (swapped), z=2 V (unswapped -> V^T (b,h,d,n)).
__global__ __launch_bounds__(512, 2) void k_qkv(
    const short* __restrict__ A, const short* __restrict__ WT,
    const float* __restrict__ bq, const float* __restrict__ bk,
    const float* __restrict__ bv, short* __restrict__ oq,
    short* __restrict__ ok, short* __restrict__ ovt) {
  const int orig = blockIdx.x;                 // 0..767
  const int xcd = orig & 7, r = orig >> 3;     // r: 0..95
  const int tml = r / 12, rem = r % 12;
  const int z = rem >> 2, tnl = rem & 3;
  const int tm = (xcd * 8 + tml) * 256, tn = tnl * 256;
  const short* Bt = WT + (size_t)z * HSZ * HSZ;

  __shared__ __align__(16) short a_lds[2][256][64];
  __shared__ __align__(16) short b_lds[2][256][64];

  const int tid = threadIdx.x, lane = tid & 63, wave = tid >> 6;
  const int lq = lane & 15, g = lane >> 4;
  const int wm = wave >> 2, wn = wave & 3;

  f32x4 acc[8][4] = {};

  if (z == 2) {
    gemm8_core<false>(A, Bt, tm, tn, a_lds, b_lds, acc, wave, lane);
    // unswapped: lane holds 4 consecutive tokens (rows) for one d-col
#pragma unroll
    for (int j = 0; j < 4; ++j) {
      const int col = tn + wn * 64 + j * 16 + lq;
      const int hh = col >> 6, dd = col & 63;
      const float bi = bv[col];
#pragma unroll
      for (int i = 0; i < 8; ++i) {
        const int nrow = tm + wm * 128 + i * 16 + g * 4;
        const int bb = nrow >> 12, nn = nrow & (N_ - 1);
        uint2 w;
        w.x = pack2(acc[i][j][0] + bi, acc[i][j][1] + bi);
        w.y = pack2(acc[i][j][2] + bi, acc[i][j][3] + bi);
        *(uint2*)&ovt[(((size_t)bb * H_ + hh) * D_ + dd) * N_ + nn] = w;
      }
    }
  } else {
    gemm8_core<true>(A, Bt, tm, tn, a_lds, b_lds, acc, wave, lane);
    const float* bias = z ? bk : bq;
    short* outb = z ? ok : oq;
    const float alpha = z ? 1.0f : 0.125f * LOG2E;
    // swapped: lane holds 4 consecutive N-cols for one M-row
#pragma unroll
    for (int i = 0; i < 8; ++i) {
      const int row = tm + wm * 128 + i * 16 + lq;
#pragma unroll
      for (int j = 0; j < 4; ++j) {
        const int colb = tn + wn * 64 + j * 16 + g * 4;
        const float4 bi = *(const float4*)&bias[colb];
        const int bb = row >> 12, nn = row & (N_ - 1);
        const int hh = colb >> 6, dd = colb & 63;
        uint2 w;
        w.x = pack2((acc[i][j][0] + bi.x) * alpha,
                    (acc[i][j][1] + bi.y) * alpha);
        w.y = pack2((acc[i][j][2] + bi.z) * alpha,
                    (acc[i][j][3] + bi.w) * alpha);
        *(uint2*)&outb[(((size_t)bb * H_ + hh) * N_ + nn) * D_ + dd] = w;
      }
    }
  }
}

// Output projection: y = ctx @ Wo^T + bo + xs (f32). grid 256, 512 thr.
__global__ __launch_bounds__(512, 2) void k_out(
    const short* __restrict__ A, const short* __restrict__ WT,
    const float* __restrict__ bo, const float* __restrict__ xs,
    float* __restrict__ yout) {
  const short* Bt = WT + (size_t)3 * HSZ * HSZ;

  __shared__ __align__(16) short a_lds[2][256][64];
  __shared__ __align__(16) short b_lds[2][256][64];

  const int tid = threadIdx.x, lane = tid & 63, wave = tid >> 6;
  const int lq = lane & 15, g = lane >> 4;
  const int wm = wave >> 2, wn = wave & 3;
  const int orig = blockIdx.x;                 // 0..255
  const int xcd = orig & 7, r = orig >> 3;     // r: 0..31
  const int tml = r >> 2, tnl = r & 3;
  const int tm = (xcd * 8 + tml) * 256, tn = tnl * 256;

  f32x4 acc[8][4] = {};
  gemm8_core<true>(A, Bt, tm, tn, a_lds, b_lds, acc, wave, lane);

#pragma unroll
  for (int i = 0; i < 8; ++i) {
    const int row = tm + wm * 128 + i * 16 + lq;
#pragma unroll
    for (int j = 0; j < 4; ++j) {
      const int colb = tn + wn * 64 + j * 16 + g * 4;
      const float4 bi = *(const float4*)&bo[colb];
      const size_t idx = (size_t)row * HSZ + colb;
      const float4 xv = *(const float4*)&xs[idx];
      float4 yv;
      yv.x = acc[i][j][0] + bi.x + xv.x;
      yv.y = acc[i][j][1] + bi.y + xv.y;
      yv.z = acc[i][j][2] + bi.z + xv.z;
      yv.w = acc[i][j][3] + bi.w + xv.w;
      *(float4*)&yout[idx] = yv;
    }
  }
}

// ---------------- BigBird block-sparse attention ----------------
// (unchanged from R12): denominator on the MFMA pipe (ones-column), bias as
// MFMA C-in, XOR-swizzled K/V^T LDS, XCD-grouped grid, uniform-shift softmax.
__global__ __launch_bounds__(256) void k_attn(
    const short* __restrict__ Q, const short* __restrict__ K,
    const short* __restrict__ VT, const int* __restrict__ mask,
    const int* __restrict__ rnd, short* __restrict__ ctx,
    float* __restrict__ pO, float* __restrict__ pm, float* __restrict__ pl) {
  const int orig = blockIdx.x;                 // 0..4991
  const int swg = (orig & 7) * 624 + (orig >> 3);
  const int s = swg % 78;
  const int bh_i = swg / 78;                   // 0..63
  const int h = bh_i & 15, b = bh_i >> 4;
  const int tid = threadIdx.x, lane = tid & 63, wave = tid >> 6;
  const int g = lane >> 4, lq = lane & 15;

  __shared__ __align__(16) short k_lds[64][64];
  __shared__ __align__(16) short vt_lds[64][64];
  __shared__ __align__(16) short p_lds[4][16][72];
  __shared__ __align__(16) float bias_s[8][64];
  __shared__ int list_s[8];
  __shared__ int Ls;

  const bool mid = (s < 62);
  const int qb = mid ? (s + 1) : (((s - 62) >> 3) ? (NB_ - 1) : 0);

  if (tid == 0) {
    int L;
    if (!mid) {
      int chunk = (s - 62) & 7;
#pragma unroll
      for (int i = 0; i < 8; ++i) list_s[i] = chunk * 8 + i;
      L = 8;
    } else {
      const int* rp = rnd + ((size_t)h * (NB_ - 2) + (qb - 1)) * R_;
      int n;
      if (qb == 1) {
        list_s[0] = 0; list_s[1] = 1; list_s[2] = 2; list_s[3] = NB_ - 1; n = 4;
      } else if (qb == NB_ - 2) {
        list_s[0] = NB_ - 3; list_s[1] = NB_ - 2; list_s[2] = NB_ - 1;
        list_s[3] = 0; n = 4;
      } else {
        list_s[0] = qb - 1; list_s[1] = qb; list_s[2] = qb + 1;
        list_s[3] = 0; list_s[4] = NB_ - 1; n = 5;
      }
      for (int j = 0; j < R_; ++j) list_s[n + j] = rp[j];
      L = n + R_;
      for (int i = L; i < 8; ++i) list_s[i] = 0;   // keep indices safe
    }
    Ls = L;
  }

  const size_t bh = (size_t)b * H_ + h;
  const size_t qrow = bh * N_ + (size_t)qb * 64 + wave * 16 + lq;
  s16x8 qf0 = *(const s16x8*)&Q[qrow * D_ + g * 8];
  s16x8 qf1 = *(const s16x8*)&Q[qrow * D_ + 32 + g * 8];

  __syncthreads();
  const int L = Ls;

  const int r0 = tid >> 3, sg = tid & 7;     // r0: 0..31, two rows each
  const int csl = (sg ^ (r0 & 7)) * 8;       // swizzled 16B slot (write side)
  const int sw = (lq & 7);                   // read-side row XOR key

  const short* Kb = K + bh * (size_t)N_ * D_;
  const short* Vb = VT + bh * (size_t)D_ * N_;
  const int* mb = mask + (size_t)b * N_;

  // precompute bias rows for all 8 list slots (ordered by in-loop barrier)
  for (int t = tid; t < 512; t += 256) {
    const int i = t >> 6, kk2 = t & 63;
    bias_s[i][kk2] =
        (1.0f - (float)mb[list_s[i] * 64 + kk2]) * (NEGV * LOG2E);
  }

  s16x8 kr0, kr1, vr0, vr1;
  {
    const int kb = list_s[0];
    const short* kp = Kb + (size_t)kb * 64 * D_;
    const short* vp = Vb + (size_t)kb * 64;
    kr0 = *(const s16x8*)&kp[(size_t)r0 * D_ + sg * 8];
    kr1 = *(const s16x8*)&kp[(size_t)(r0 + 32) * D_ + sg * 8];
    vr0 = *(const s16x8*)&vp[(size_t)r0 * N_ + sg * 8];
    vr1 = *(const s16x8*)&vp[(size_t)(r0 + 32) * N_ + sg * 8];
  }

  s16x8 ones;
#pragma unroll
  for (int u = 0; u < 8; ++u) ones[u] = (short)0x3F80;  // bf16 1.0

  f32x4 o[4] = {};
  f32x4 osum = {};
  float mshift = 0.0f;

  for (int it = 0; it < L; ++it) {
    *(s16x8*)&k_lds[r0][csl] = kr0;
    *(s16x8*)&k_lds[r0 + 32][csl] = kr1;
    *(s16x8*)&vt_lds[r0][csl] = vr0;
    *(s16x8*)&vt_lds[r0 + 32][csl] = vr1;
    if (it + 1 < L) {
      const int kb = list_s[it + 1];
      const short* kp = Kb + (size_t)kb * 64 * D_;
      const short* vp = Vb + (size_t)kb * 64;
      kr0 = *(const s16x8*)&kp[(size_t)r0 * D_ + sg * 8];
      kr1 = *(const s16x8*)&kp[(size_t)(r0 + 32) * D_ + sg * 8];
      vr0 = *(const s16x8*)&vp[(size_t)r0 * N_ + sg * 8];
      vr1 = *(const s16x8*)&vp[(size_t)(r0 + 32) * N_ + sg * 8];
    }
    __syncthreads();

    // S^T = K @ Q^T, bias preloaded as MFMA C-in (rows=keys, cols=queries)
    f32x4 st[4];
#pragma unroll
    for (int f = 0; f < 4; ++f) {
      f32x4 a0 = *(const f32x4*)&bias_s[it][f * 16 + g * 4];
      s16x8 af0 = *(const s16x8*)&k_lds[f * 16 + lq][(g ^ sw) * 8];
      s16x8 af1 = *(const s16x8*)&k_lds[f * 16 + lq][((4 + g) ^ sw) * 8];
      a0 = mfma16(af0, qf0, a0);
      a0 = mfma16(af1, qf1, a0);
      st[f] = a0;
    }

    // exp2 (uniform-shift online softmax; fast path while mshift==0)
    if (mshift == 0.0f) {
#pragma unroll
      for (int f = 0; f < 4; ++f)
#pragma unroll
        for (int e = 0; e < 4; ++e) st[f][e] = exp2f(st[f][e]);
    } else {
#pragma unroll
      for (int f = 0; f < 4; ++f)
#pragma unroll
        for (int e = 0; e < 4; ++e) st[f][e] = exp2f(st[f][e] - mshift);
    }

    // P rows to per-wave LDS (row = query lq, cols = keys)
#pragma unroll
    for (int f = 0; f < 4; ++f) {
      uint2 w = make_uint2(pack2(st[f][0], st[f][1]),
                           pack2(st[f][2], st[f][3]));
      *(uint2*)&p_lds[wave][lq][f * 16 + g * 4] = w;
    }

    // O += P @ V ; denominator via ones-column on the MFMA pipe
#pragma unroll
    for (int kk = 0; kk < 2; ++kk) {
      s16x8 pa = *(const s16x8*)&p_lds[wave][lq][kk * 32 + g * 8];
#pragma unroll
      for (int j = 0; j < 4; ++j) {
        s16x8 bv =
            *(const s16x8*)&vt_lds[j * 16 + lq][((kk * 4 + g) ^ sw) * 8];
        o[j] = mfma16(pa, bv, o[j]);
      }
      osum = mfma16(pa, ones, osum);
    }

    // overflow guard: uniform shift (never fires on typical data)
    float om = fmaxf(fmaxf(osum[0], osum[1]), fmaxf(osum[2], osum[3]));
    if (__any(om > 16777216.0f)) {
#pragma unroll
      for (int j = 0; j < 4; ++j) o[j] *= 5.9604645e-08f;  // 2^-24
      osum *= 5.9604645e-08f;
      mshift += 24.0f;
    }
    __syncthreads();
  }

  if (mid) {
    float rs[4];
#pragma unroll
    for (int e = 0; e < 4; ++e)
      rs[e] = (float)mb[qb * 64 + wave * 16 + g * 4 + e] /
              fmaxf(osum[e], 1e-30f);
#pragma unroll
    for (int j = 0; j < 4; ++j) {
      k_lds[wave * 16 + g * 4 + 0][j * 16 + lq] = f2b(o[j][0] * rs[0]);
      k_lds[wave * 16 + g * 4 + 1][j * 16 + lq] = f2b(o[j][1] * rs[1]);
      k_lds[wave * 16 + g * 4 + 2][j * 16 + lq] = f2b(o[j][2] * rs[2]);
      k_lds[wave * 16 + g * 4 + 3][j * 16 + lq] = f2b(o[j][3] * rs[3]);
    }
    __syncthreads();
#pragma unroll
    for (int pp = 0; pp < 2; ++pp) {
      int c = tid + pp * 256;
      int row = c >> 3, seg = c & 7;
      *(s16x8*)&ctx[((size_t)b * N_ + qb * 64 + row) * HSZ + h * D_ + seg * 8] =
          *(const s16x8*)&k_lds[row][seg * 8];
    }
  } else {
    const int e2 = s - 62;
    const int qsel = e2 >> 3, chunk = e2 & 7;
    const size_t eidx = (bh * 2 + qsel) * 8 + chunk;
    float* po = pO + eidx * 4096;
#pragma unroll
    for (int j = 0; j < 4; ++j)
#pragma unroll
      for (int e = 0; e < 4; ++e)
        po[(wave * 16 + g * 4 + e) * 64 + j * 16 + lq] = o[j][e];
    if (lq == 0) {
#pragma unroll
      for (int e = 0; e < 4; ++e) {
        pm[eidx * 64 + wave * 16 + g * 4 + e] = mshift;
        pl[eidx * 64 + wave * 16 + g * 4 + e] = osum[e];
      }
    }
  }
}

// ---------------- combine edge partials (log2-domain shifts) ----------------
__global__ __launch_bounds__(256) void k_comb(
    const float* __restrict__ pO, const float* __restrict__ pm,
    const float* __restrict__ pl, const int* __restrict__ mask,
    short* __restrict__ ctx) {
  const int qsel = blockIdx.x, h = blockIdx.y, b = blockIdx.z;
  const int qb = qsel ? NB_ - 1 : 0;
  const int tid = threadIdx.x;
  const int q = tid >> 2, dq = tid & 3;
  const size_t base = (((size_t)b * H_ + h) * 2 + qsel) * 8;

  float mv[8];
  float M = -INFINITY;
#pragma unroll
  for (int i = 0; i < 8; ++i) {
    mv[i] = pm[(base + i) * 64 + q];
    M = fmaxf(M, mv[i]);
  }
  float Lsum = 0.0f;
#pragma unroll
  for (int i = 0; i < 8; ++i) {
    float w = exp2f(mv[i] - M);
    mv[i] = w;
    Lsum += pl[(base + i) * 64 + q] * w;
  }
  f32x4 acc[4] = {};
#pragma unroll
  for (int i = 0; i < 8; ++i) {
    const float* p = pO + (base + i) * 4096 + q * 64 + dq * 16;
    float w = mv[i];
#pragma unroll
    for (int u = 0; u < 4; ++u) {
      f32x4 v = *(const f32x4*)&p[u * 4];
      acc[u] += v * w;
    }
  }
  float sc = (float)mask[(size_t)b * N_ + qb * 64 + q] / fmaxf(Lsum, 1e-30f);
  s16x8 out0, out1;
#pragma unroll
  for (int u = 0; u < 8; ++u) {
    out0[u] = f2b(acc[u >> 2][u & 3] * sc);
    out1[u] = f2b(acc[2 + (u >> 2)][u & 3] * sc);
  }
  short* dst = &ctx[((size_t)b * N_ + qb * 64 + q) * HSZ + h * D_ + dq * 16];
  *(s16x8*)dst = out0;
  *(s16x8*)(dst + 8) = out1;
}

// ---------------- LayerNorm (in place on y) ----------------
__global__ __launch_bounds__(256) void k_ln(float* __restrict__ y,
                                            const float* __restrict__ gamma,
                                            const float* __restrict__ beta) {
  const int row = blockIdx.x, tid = threadIdx.x, lane = tid & 63,
            wave = tid >> 6;
  __shared__ float s_sum[4], s_sq[4];
  float4 v = *(const float4*)&y[(size_t)row * HSZ + tid * 4];
  float s = v.x + v.y + v.z + v.w;
  float q = v.x * v.x + v.y * v.y + v.z * v.z + v.w * v.w;
#pragma unroll
  for (int m = 1; m <= 32; m <<= 1) {
    s += __shfl_xor(s, m);
    q += __shfl_xor(q, m);
  }
  if (lane == 0) { s_sum[wave] = s; s_sq[wave] = q; }
  __syncthreads();
  float S = s_sum[0] + s_sum[1] + s_sum[2] + s_sum[3];
  float Qs = s_sq[0] + s_sq[1] + s_sq[2] + s_sq[3];
  float mu = S * (1.0f / HSZ);
  float var = Qs * (1.0f / HSZ) - mu * mu;
  float r = rsqrtf(var + 1e-12f);
  float4 g = *(const float4*)&gamma[tid * 4];
  float4 be = *(const float4*)&beta[tid * 4];
  float4 outv;
  outv.x = (v.x - mu) * r * g.x + be.x;
  outv.y = (v.y - mu) * r * g.y + be.y;
  outv.z = (v.z - mu) * r * g.z + be.z;
  outv.w = (v.w - mu) * r * g.w + be.w;
  *(float4*)&y[(size_t)row * HSZ + tid * 4] = outv;
}

// ---------------- launch ----------------
extern "C" void kernel_launch(void* const* d_in, const int* in_sizes, int n_in,
                              void* d_out, int out_size, void* d_ws,
                              size_t ws_size, hipStream_t stream) {
  const float* xs = (const float*)d_in[0];
  const int* mask = (const int*)d_in[1];
  const float* Wq = (const float*)d_in[2];
  const float* bq = (const float*)d_in[3];
  const float* Wk = (const float*)d_in[4];
  const float* bk = (const float*)d_in[5];
  const float* Wv = (const float*)d_in[6];
  const float* bv = (const float*)d_in[7];
  const float* Wo = (const float*)d_in[8];
  const float* bo = (const float*)d_in[9];
  const float* gamma = (const float*)d_in[10];
  const float* beta = (const float*)d_in[11];
  const int* rnd = (const int*)d_in[12];
  float* yout = (float*)d_out;

  char* ws = (char*)d_ws;
  const size_t SZ_XS = (size_t)M_ * HSZ * 2;       // 32 MB
  const size_t SZ_WT = (size_t)4 * HSZ * HSZ * 2;  // 8 MB
  short* xsb = (short*)ws;                         // also reused as ctx
  short* wt = (short*)(ws + SZ_XS);
  short* qbuf = (short*)(ws + SZ_XS + SZ_WT);
  short* kbuf = qbuf + (size_t)M_ * HSZ;
  short* vtb = kbuf + (size_t)M_ * HSZ;            // V^T (b,h,d,n)
  char* after = ws + SZ_XS + SZ_WT + 3 * SZ_XS;
  float* pO = (float*)(after + (1 << 20));         // 1024*4096 f32 = 16 MB
  float* pm = pO + (size_t)1024 * 4096;            // 256 KB
  float* pl = pm + (size_t)1024 * 64;              // 256 KB

  k_prep<<<9216, 256, 0, stream>>>(xs, xsb, Wq, Wk, Wv, Wo, wt);
  k_qkv<<<768, 512, 0, stream>>>(xsb, wt, bq, bk, bv, qbuf, kbuf, vtb);
  k_attn<<<4992, 256, 0, stream>>>(qbuf, kbuf, vtb, mask, rnd, xsb, pO, pm,
                                   pl);
  k_comb<<<dim3(2, H_, B_), 256, 0, stream>>>(pO, pm, pl, mask, xsb);
  k_out<<<256, 512, 0, stream>>>(xsb, wt, bo, xs, yout);
  k_ln<<<M_, 256, 0, stream>>>(yout, gamma, beta);
}

// Round 14
// 323.602 us; speedup vs baseline: 1.0621x; 1.0054x over previous
//
#include <hip/hip_runtime.h>
#include <hip/hip_bf16.h>

#define B_   4
#define N_   4096
#define HSZ  1024
#define H_   16
#define D_   64
#define NB_  64
#define R_   3
#define M_   (B_*N_)          // 16384 rows
#define NEGV (-1e4f)
#define LOG2E 1.4426950408889634f

typedef float f32x4 __attribute__((ext_vector_type(4)));
typedef short s16x8 __attribute__((ext_vector_type(8)));
typedef __bf16 b16x8 __attribute__((ext_vector_type(8)));

__device__ __forceinline__ f32x4 mfma16(s16x8 a, s16x8 b, f32x4 c) {
  return __builtin_amdgcn_mfma_f32_16x16x32_bf16(
      __builtin_bit_cast(b16x8, a), __builtin_bit_cast(b16x8, b), c, 0, 0, 0);
}

__device__ __forceinline__ short f2b(float x) {
  __hip_bfloat16 h = __float2bfloat16(x);
  return (short)__builtin_bit_cast(unsigned short, h);
}

__device__ __forceinline__ unsigned pack2(float a, float b) {
  return (unsigned)(unsigned short)f2b(a) |
         ((unsigned)(unsigned short)f2b(b) << 16);
}

// async global->LDS, 16B per lane; LDS dest = wave-uniform base + lane*16
__device__ __forceinline__ void gl_lds16(const short* g, short* l) {
  __builtin_amdgcn_global_load_lds(
      (const __attribute__((address_space(1))) unsigned int*)g,
      (__attribute__((address_space(3))) unsigned int*)l, 16, 0, 0);
}

// ---------------- fused conversions: xs->bf16 + weight transpose ----------
__global__ __launch_bounds__(256) void k_prep(const float* __restrict__ in,
                                              short* __restrict__ out,
                                              const float* __restrict__ Wq,
                                              const float* __restrict__ Wk,
                                              const float* __restrict__ Wv,
                                              const float* __restrict__ Wo,
                                              short* __restrict__ wt) {
  const int tid = threadIdx.x;
  if (blockIdx.x < 8192) {
    size_t i = ((size_t)blockIdx.x * 256 + tid) * 8;
    float4 a = *(const float4*)&in[i];
    float4 b = *(const float4*)&in[i + 4];
    s16x8 o;
    o[0] = f2b(a.x); o[1] = f2b(a.y); o[2] = f2b(a.z); o[3] = f2b(a.w);
    o[4] = f2b(b.x); o[5] = f2b(b.y); o[6] = f2b(b.z); o[7] = f2b(b.w);
    *(s16x8*)&out[i] = o;
    return;
  }
  const int bid = blockIdx.x - 8192;            // 0..1023
  const int z = bid >> 8;
  const int rest = bid & 255;
  const int tk = (rest >> 4) * 64, tn = (rest & 15) * 64;
  const float* src = (z == 0) ? Wq : (z == 1) ? Wk : (z == 2) ? Wv : Wo;
  short* dst = wt + (size_t)z * HSZ * HSZ;
  __shared__ __align__(16) float t[64][68];
#pragma unroll
  for (int r = 0; r < 4; ++r) {
    int c = tid + r * 256;
    int row = c >> 4, seg = c & 15;
    *(float4*)&t[row][seg * 4] =
        *(const float4*)&src[(size_t)(tk + row) * HSZ + tn + seg * 4];
  }
  __syncthreads();
#pragma unroll
  for (int r = 0; r < 2; ++r) {
    int c = tid + r * 256;
    int row = c >> 3, seg = c & 7;
    s16x8 o;
#pragma unroll
    for (int u = 0; u < 8; ++u) o[u] = f2b(t[seg * 8 + u][row]);
    *(s16x8*)&dst[(size_t)(tn + row) * HSZ + tk + seg * 8] = o;
  }
}

// ---------------- 256x256 8-phase GEMM core (T3+T4) ----------------
template <bool SWAP>
__device__ __forceinline__ void gemm8_core(
    const short* __restrict__ A, const short* __restrict__ Bt, int tm, int tn,
    short (&a_lds)[2][256][64], short (&b_lds)[2][256][64],
    f32x4 (&acc)[8][4], int wave, int lane) {
  const int lq = lane & 15, g = lane >> 4;
  const int wm = wave >> 2, wn = wave & 3;
  const int sl8 = lane >> 3;
  const int sc = ((lane & 7) ^ sl8) * 8;   // pre-swizzled global 16B slot

  auto ST_A = [&](int buf, int kt, int h) {
#pragma unroll
    for (int u = 0; u < 2; ++u) {
      const int rbase = h * 128 + wave * 8 + u * 64;
      gl_lds16(&A[(size_t)(tm + rbase + sl8) * HSZ + kt * 64 + sc],
               &a_lds[buf][rbase][0]);
    }
  };
  auto ST_B = [&](int buf, int kt, int h) {
#pragma unroll
    for (int u = 0; u < 2; ++u) {
      const int rbase = h * 128 + wave * 8 + u * 64;
      gl_lds16(&Bt[(size_t)(tn + rbase + sl8) * HSZ + kt * 64 + sc],
               &b_lds[buf][rbase][0]);
    }
  };

  s16x8 bf[4][2];
  auto LOADB = [&](int buf) {
#pragma unroll
    for (int j = 0; j < 4; ++j) {
      const int row = wn * 64 + j * 16 + lq;
#pragma unroll
      for (int kk = 0; kk < 2; ++kk)
        bf[j][kk] =
            *(const s16x8*)&b_lds[buf][row][((kk * 4 + g) ^ (lq & 7)) * 8];
    }
  };
  auto PH = [&](int buf, int m0) {
    s16x8 af[2][2];
#pragma unroll
    for (int i = 0; i < 2; ++i) {
      const int row = wm * 128 + (m0 + i) * 16 + lq;
#pragma unroll
      for (int kk = 0; kk < 2; ++kk)
        af[i][kk] =
            *(const s16x8*)&a_lds[buf][row][((kk * 4 + g) ^ (lq & 7)) * 8];
    }
    __builtin_amdgcn_s_setprio(1);
#pragma unroll
    for (int i = 0; i < 2; ++i)
#pragma unroll
      for (int j = 0; j < 4; ++j)
#pragma unroll
        for (int kk = 0; kk < 2; ++kk)
          acc[m0 + i][j] = SWAP
                               ? mfma16(bf[j][kk], af[i][kk], acc[m0 + i][j])
                               : mfma16(af[i][kk], bf[j][kk], acc[m0 + i][j]);
    __builtin_amdgcn_s_setprio(0);
    __builtin_amdgcn_s_barrier();
  };

  // prologue: tile0 (A+B) + tile1 B  -> 12 loads/thread outstanding
  ST_A(0, 0, 0); ST_A(0, 0, 1);
  ST_B(0, 0, 0); ST_B(0, 0, 1);
  ST_B(1, 1, 0); ST_B(1, 1, 1);

  for (int p = 0; p < 8; ++p) {
    const int t = 2 * p;
    // P0
    ST_A(1, t + 1, 0); ST_A(1, t + 1, 1);
    asm volatile("s_waitcnt vmcnt(8)" ::: "memory");
    __builtin_amdgcn_s_barrier();
    LOADB(0);
    PH(0, 0);
    // P1
    if (t + 2 < 16) { ST_B(0, t + 2, 0); ST_B(0, t + 2, 1); }
    PH(0, 2);
    // P2
    PH(0, 4);
    // P3
    PH(0, 6);
    // P4
    if (t + 2 < 16) { ST_A(0, t + 2, 0); ST_A(0, t + 2, 1); }
    if (p < 7) {
      asm volatile("s_waitcnt vmcnt(8)" ::: "memory");
    } else {
      asm volatile("s_waitcnt vmcnt(0)" ::: "memory");
    }
    __builtin_amdgcn_s_barrier();
    LOADB(1);
    PH(1, 0);
    // P5
    if (t + 3 < 16) { ST_B(1, t + 3, 0); ST_B(1, t + 3, 1); }
    PH(1, 2);
    // P6
    PH(1, 4);
    // P7
    PH(1, 6);
  }
}

// QKV projection: grid 768 (1D, XCD-grouped), 512 thr. z=0 Q (swapped,
// scaled), z=1 K (swapped), z=2 V (unswapped -> V^T (b,h,d,n)).
__global__ __launch_bounds__(512) void k_qkv(
    const short* __restrict__ A, const short* __restrict__ WT,
    const float* __restrict__ bq, const float* __restrict__ bk,
    const float* __restrict__ bv, short* __restrict__ oq,
    short* __restrict__ ok, short* __restrict__ ovt) {
  const int orig = blockIdx.x;                 // 0..767
  const int xcd = orig & 7, r = orig >> 3;     // r: 0..95
  const int tml = r / 12, rem = r % 12;
  const int z = rem >> 2, tnl = rem & 3;
  const int tm = (xcd * 8 + tml) * 256, tn = tnl * 256;
  const short* Bt = WT + (size_t)z * HSZ * HSZ;

  __shared__ __align__(16) short a_lds[2][256][64];
  __shared__ __align__(16) short b_lds[2][256][64];

  const int tid = threadIdx.x, lane = tid & 63, wave = tid >> 6;
  const int lq = lane & 15, g = lane >> 4;
  const int wm = wave >> 2, wn = wave & 3;

  f32x4 acc[8][4] = {};

  if (z == 2) {
    gemm8_core<false>(A, Bt, tm, tn, a_lds, b_lds, acc, wave, lane);
    // unswapped: lane holds 4 consecutive tokens (rows) for one d-col
#pragma unroll
    for (int j = 0; j < 4; ++j) {
      const int col = tn + wn * 64 + j * 16 + lq;
      const int hh = col >> 6, dd = col & 63;
      const float bi = bv[col];
#pragma unroll
      for (int i = 0; i < 8; ++i) {
        const int nrow = tm + wm * 128 + i * 16 + g * 4;
        const int bb = nrow >> 12, nn = nrow & (N_ - 1);
        uint2 w;
        w.x = pack2(acc[i][j][0] + bi, acc[i][j][1] + bi);
        w.y = pack2(acc[i][j][2] + bi, acc[i][j][3] + bi);
        *(uint2*)&ovt[(((size_t)bb * H_ + hh) * D_ + dd) * N_ + nn] = w;
      }
    }
  } else {
    gemm8_core<true>(A, Bt, tm, tn, a_lds, b_lds, acc, wave, lane);
    const float* bias = z ? bk : bq;
    short* outb = z ? ok : oq;
    const float alpha = z ? 1.0f : 0.125f * LOG2E;
    // swapped: lane holds 4 consecutive N-cols for one M-row
#pragma unroll
    for (int i = 0; i < 8; ++i) {
      const int row = tm + wm * 128 + i * 16 + lq;
#pragma unroll
      for (int j = 0; j < 4; ++j) {
        const int colb = tn + wn * 64 + j * 16 + g * 4;
        const float4 bi = *(const float4*)&bias[colb];
        const int bb = row >> 12, nn = row & (N_ - 1);
        const int hh = colb >> 6, dd = colb & 63;
        uint2 w;
        w.x = pack2((acc[i][j][0] + bi.x) * alpha,
                    (acc[i][j][1] + bi.y) * alpha);
        w.y = pack2((acc[i][j][2] + bi.z) * alpha,
                    (acc[i][j][3] + bi.w) * alpha);
        *(uint2*)&outb[(((size_t)bb * H_ + hh) * N_ + nn) * D_ + dd] = w;
      }
    }
  }
}

// Output projection: y = ctx @ Wo^T + bo + xs (f32). grid 256, 512 thr.
__global__ __launch_bounds__(512) void k_out(
    const short* __restrict__ A, const short* __restrict__ WT,
    const float* __restrict__ bo, const float* __restrict__ xs,
    float* __restrict__ yout) {
  const short* Bt = WT + (size_t)3 * HSZ * HSZ;

  __shared__ __align__(16) short a_lds[2][256][64];
  __shared__ __align__(16) short b_lds[2][256][64];

  const int tid = threadIdx.x, lane = tid & 63, wave = tid >> 6;
  const int lq = lane & 15, g = lane >> 4;
  const int wm = wave >> 2, wn = wave & 3;
  const int orig = blockIdx.x;                 // 0..255
  const int xcd = orig & 7, r = orig >> 3;     // r: 0..31
  const int tml = r >> 2, tnl = r & 3;
  const int tm = (xcd * 8 + tml) * 256, tn = tnl * 256;

  f32x4 acc[8][4] = {};
  gemm8_core<true>(A, Bt, tm, tn, a_lds, b_lds, acc, wave, lane);

#pragma unroll
  for (int i = 0; i < 8; ++i) {
    const int row = tm + wm * 128 + i * 16 + lq;
#pragma unroll
    for (int j = 0; j < 4; ++j) {
      const int colb = tn + wn * 64 + j * 16 + g * 4;
      const float4 bi = *(const float4*)&bo[colb];
      const size_t idx = (size_t)row * HSZ + colb;
      const float4 xv = *(const float4*)&xs[idx];
      float4 yv;
      yv.x = acc[i][j][0] + bi.x + xv.x;
      yv.y = acc[i][j][1] + bi.y + xv.y;
      yv.z = acc[i][j][2] + bi.z + xv.z;
      yv.w = acc[i][j][3] + bi.w + xv.w;
      *(float4*)&yout[idx] = yv;
    }
  }
}

// ---------------- BigBird block-sparse attention ----------------
// R13 structure + double-buffered K/V^T LDS: ONE barrier per iter (commit
// barrier); fast waves write the other buffer so no trailing sync needed.
__global__ __launch_bounds__(256) void k_attn(
    const short* __restrict__ Q, const short* __restrict__ K,
    const short* __restrict__ VT, const int* __restrict__ mask,
    const int* __restrict__ rnd, short* __restrict__ ctx,
    float* __restrict__ pO, float* __restrict__ pm, float* __restrict__ pl) {
  const int orig = blockIdx.x;                 // 0..4991
  const int swg = (orig & 7) * 624 + (orig >> 3);
  const int s = swg % 78;
  const int bh_i = swg / 78;                   // 0..63
  const int h = bh_i & 15, b = bh_i >> 4;
  const int tid = threadIdx.x, lane = tid & 63, wave = tid >> 6;
  const int g = lane >> 4, lq = lane & 15;

  __shared__ __align__(16) short k_lds[2][64][64];
  __shared__ __align__(16) short vt_lds[2][64][64];
  __shared__ __align__(16) short p_lds[4][16][72];
  __shared__ __align__(16) float bias_s[8][64];
  __shared__ int list_s[8];
  __shared__ int Ls;

  const bool mid = (s < 62);
  const int qb = mid ? (s + 1) : (((s - 62) >> 3) ? (NB_ - 1) : 0);

  if (tid == 0) {
    int L;
    if (!mid) {
      int chunk = (s - 62) & 7;
#pragma unroll
      for (int i = 0; i < 8; ++i) list_s[i] = chunk * 8 + i;
      L = 8;
    } else {
      const int* rp = rnd + ((size_t)h * (NB_ - 2) + (qb - 1)) * R_;
      int n;
      if (qb == 1) {
        list_s[0] = 0; list_s[1] = 1; list_s[2] = 2; list_s[3] = NB_ - 1; n = 4;
      } else if (qb == NB_ - 2) {
        list_s[0] = NB_ - 3; list_s[1] = NB_ - 2; list_s[2] = NB_ - 1;
        list_s[3] = 0; n = 4;
      } else {
        list_s[0] = qb - 1; list_s[1] = qb; list_s[2] = qb + 1;
        list_s[3] = 0; list_s[4] = NB_ - 1; n = 5;
      }
      for (int j = 0; j < R_; ++j) list_s[n + j] = rp[j];
      L = n + R_;
      for (int i = L; i < 8; ++i) list_s[i] = 0;   // keep indices safe
    }
    Ls = L;
  }

  const size_t bh = (size_t)b * H_ + h;
  const size_t qrow = bh * N_ + (size_t)qb * 64 + wave * 16 + lq;
  s16x8 qf0 = *(const s16x8*)&Q[qrow * D_ + g * 8];
  s16x8 qf1 = *(const s16x8*)&Q[qrow * D_ + 32 + g * 8];

  __syncthreads();
  const int L = Ls;

  const int r0 = tid >> 3, sg = tid & 7;     // r0: 0..31, two rows each
  const int csl = (sg ^ (r0 & 7)) * 8;       // swizzled 16B slot (write side)
  const int sw = (lq & 7);                   // read-side row XOR key

  const short* Kb = K + bh * (size_t)N_ * D_;
  const short* Vb = VT + bh * (size_t)D_ * N_;
  const int* mb = mask + (size_t)b * N_;

  // precompute bias rows for all 8 list slots
  for (int t = tid; t < 512; t += 256) {
    const int i = t >> 6, kk2 = t & 63;
    bias_s[i][kk2] =
        (1.0f - (float)mb[list_s[i] * 64 + kk2]) * (NEGV * LOG2E);
  }

  s16x8 kr0, kr1, vr0, vr1;
  {
    const int kb = list_s[0];
    const short* kp = Kb + (size_t)kb * 64 * D_;
    const short* vp = Vb + (size_t)kb * 64;
    kr0 = *(const s16x8*)&kp[(size_t)r0 * D_ + sg * 8];
    kr1 = *(const s16x8*)&kp[(size_t)(r0 + 32) * D_ + sg * 8];
    vr0 = *(const s16x8*)&vp[(size_t)r0 * N_ + sg * 8];
    vr1 = *(const s16x8*)&vp[(size_t)(r0 + 32) * N_ + sg * 8];
  }

  s16x8 ones;
#pragma unroll
  for (int u = 0; u < 8; ++u) ones[u] = (short)0x3F80;  // bf16 1.0

  f32x4 o[4] = {};
  f32x4 osum = {};
  float mshift = 0.0f;

  for (int it = 0; it < L; ++it) {
    const int buf = it & 1;
    // commit staged tile to LDS buf (XOR-swizzled), issue next tile's loads
    *(s16x8*)&k_lds[buf][r0][csl] = kr0;
    *(s16x8*)&k_lds[buf][r0 + 32][csl] = kr1;
    *(s16x8*)&vt_lds[buf][r0][csl] = vr0;
    *(s16x8*)&vt_lds[buf][r0 + 32][csl] = vr1;
    if (it + 1 < L) {
      const int kb = list_s[it + 1];
      const short* kp = Kb + (size_t)kb * 64 * D_;
      const short* vp = Vb + (size_t)kb * 64;
      kr0 = *(const s16x8*)&kp[(size_t)r0 * D_ + sg * 8];
      kr1 = *(const s16x8*)&kp[(size_t)(r0 + 32) * D_ + sg * 8];
      vr0 = *(const s16x8*)&vp[(size_t)r0 * N_ + sg * 8];
      vr1 = *(const s16x8*)&vp[(size_t)(r0 + 32) * N_ + sg * 8];
    }
    __syncthreads();  // all waves committed buf; prior buf reads are 2 iters old

    // S^T = K @ Q^T, bias preloaded as MFMA C-in (rows=keys, cols=queries)
    f32x4 st[4];
#pragma unroll
    for (int f = 0; f < 4; ++f) {
      f32x4 a0 = *(const f32x4*)&bias_s[it][f * 16 + g * 4];
      s16x8 af0 = *(const s16x8*)&k_lds[buf][f * 16 + lq][(g ^ sw) * 8];
      s16x8 af1 = *(const s16x8*)&k_lds[buf][f * 16 + lq][((4 + g) ^ sw) * 8];
      a0 = mfma16(af0, qf0, a0);
      a0 = mfma16(af1, qf1, a0);
      st[f] = a0;
    }

    // exp2 (uniform-shift online softmax; fast path while mshift==0)
    if (mshift == 0.0f) {
#pragma unroll
      for (int f = 0; f < 4; ++f)
#pragma unroll
        for (int e = 0; e < 4; ++e) st[f][e] = exp2f(st[f][e]);
    } else {
#pragma unroll
      for (int f = 0; f < 4; ++f)
#pragma unroll
        for (int e = 0; e < 4; ++e) st[f][e] = exp2f(st[f][e] - mshift);
    }

    // P rows to per-wave LDS (row = query lq, cols = keys)
#pragma unroll
    for (int f = 0; f < 4; ++f) {
      uint2 w = make_uint2(pack2(st[f][0], st[f][1]),
                           pack2(st[f][2], st[f][3]));
      *(uint2*)&p_lds[wave][lq][f * 16 + g * 4] = w;
    }

    // O += P @ V ; denominator via ones-column on the MFMA pipe
#pragma unroll
    for (int kk = 0; kk < 2; ++kk) {
      s16x8 pa = *(const s16x8*)&p_lds[wave][lq][kk * 32 + g * 8];
#pragma unroll
      for (int j = 0; j < 4; ++j) {
        s16x8 bv =
            *(const s16x8*)&vt_lds[buf][j * 16 + lq][((kk * 4 + g) ^ sw) * 8];
        o[j] = mfma16(pa, bv, o[j]);
      }
      osum = mfma16(pa, ones, osum);
    }

    // overflow guard: uniform shift (never fires on typical data)
    float om = fmaxf(fmaxf(osum[0], osum[1]), fmaxf(osum[2], osum[3]));
    if (__any(om > 16777216.0f)) {
#pragma unroll
      for (int j = 0; j < 4; ++j) o[j] *= 5.9604645e-08f;  // 2^-24
      osum *= 5.9604645e-08f;
      mshift += 24.0f;
    }
  }

  if (mid) {
    float rs[4];
#pragma unroll
    for (int e = 0; e < 4; ++e)
      rs[e] = (float)mb[qb * 64 + wave * 16 + g * 4 + e] /
              fmaxf(osum[e], 1e-30f);
    __syncthreads();  // ensure no wave still reads k_lds[0] (odd-L parity)
    short (*ost)[64] = k_lds[0];
#pragma unroll
    for (int j = 0; j < 4; ++j) {
      ost[wave * 16 + g * 4 + 0][j * 16 + lq] = f2b(o[j][0] * rs[0]);
      ost[wave * 16 + g * 4 + 1][j * 16 + lq] = f2b(o[j][1] * rs[1]);
      ost[wave * 16 + g * 4 + 2][j * 16 + lq] = f2b(o[j][2] * rs[2]);
      ost[wave * 16 + g * 4 + 3][j * 16 + lq] = f2b(o[j][3] * rs[3]);
    }
    __syncthreads();
#pragma unroll
    for (int pp = 0; pp < 2; ++pp) {
      int c = tid + pp * 256;
      int row = c >> 3, seg = c & 7;
      *(s16x8*)&ctx[((size_t)b * N_ + qb * 64 + row) * HSZ + h * D_ + seg * 8] =
          *(const s16x8*)&ost[row][seg * 8];
    }
  } else {
    const int e2 = s - 62;
    const int qsel = e2 >> 3, chunk = e2 & 7;
    const size_t eidx = (bh * 2 + qsel) * 8 + chunk;
    float* po = pO + eidx * 4096;
#pragma unroll
    for (int j = 0; j < 4; ++j)
#pragma unroll
      for (int e = 0; e < 4; ++e)
        po[(wave * 16 + g * 4 + e) * 64 + j * 16 + lq] = o[j][e];
    if (lq == 0) {
#pragma unroll
      for (int e = 0; e < 4; ++e) {
        pm[eidx * 64 + wave * 16 + g * 4 + e] = mshift;
        pl[eidx * 64 + wave * 16 + g * 4 + e] = osum[e];
      }
    }
  }
}

// ---------------- combine edge partials (log2-domain shifts) ----------------
__global__ __launch_bounds__(256) void k_comb(
    const float* __restrict__ pO, const float* __restrict__ pm,
    const float* __restrict__ pl, const int* __restrict__ mask,
    short* __restrict__ ctx) {
  const int qsel = blockIdx.x, h = blockIdx.y, b = blockIdx.z;
  const int qb = qsel ? NB_ - 1 : 0;
  const int tid = threadIdx.x;
  const int q = tid >> 2, dq = tid & 3;
  const size_t base = (((size_t)b * H_ + h) * 2 + qsel) * 8;

  float mv[8];
  float M = -INFINITY;
#pragma unroll
  for (int i = 0; i < 8; ++i) {
    mv[i] = pm[(base + i) * 64 + q];
    M = fmaxf(M, mv[i]);
  }
  float Lsum = 0.0f;
#pragma unroll
  for (int i = 0; i < 8; ++i) {
    float w = exp2f(mv[i] - M);
    mv[i] = w;
    Lsum += pl[(base + i) * 64 + q] * w;
  }
  f32x4 acc[4] = {};
#pragma unroll
  for (int i = 0; i < 8; ++i) {
    const float* p = pO + (base + i) * 4096 + q * 64 + dq * 16;
    float w = mv[i];
#pragma unroll
    for (int u = 0; u < 4; ++u) {
      f32x4 v = *(const f32x4*)&p[u * 4];
      acc[u] += v * w;
    }
  }
  float sc = (float)mask[(size_t)b * N_ + qb * 64 + q] / fmaxf(Lsum, 1e-30f);
  s16x8 out0, out1;
#pragma unroll
  for (int u = 0; u < 8; ++u) {
    out0[u] = f2b(acc[u >> 2][u & 3] * sc);
    out1[u] = f2b(acc[2 + (u >> 2)][u & 3] * sc);
  }
  short* dst = &ctx[((size_t)b * N_ + qb * 64 + q) * HSZ + h * D_ + dq * 16];
  *(s16x8*)dst = out0;
  *(s16x8*)(dst + 8) = out1;
}

// ---------------- LayerNorm (in place on y) ----------------
__global__ __launch_bounds__(256) void k_ln(float* __restrict__ y,
                                            const float* __restrict__ gamma,
                                            const float* __restrict__ beta) {
  const int row = blockIdx.x, tid = threadIdx.x, lane = tid & 63,
            wave = tid >> 6;
  __shared__ float s_sum[4], s_sq[4];
  float4 v = *(const float4*)&y[(size_t)row * HSZ + tid * 4];
  float s = v.x + v.y + v.z + v.w;
  float q = v.x * v.x + v.y * v.y + v.z * v.z + v.w * v.w;
#pragma unroll
  for (int m = 1; m <= 32; m <<= 1) {
    s += __shfl_xor(s, m);
    q += __shfl_xor(q, m);
  }
  if (lane == 0) { s_sum[wave] = s; s_sq[wave] = q; }
  __syncthreads();
  float S = s_sum[0] + s_sum[1] + s_sum[2] + s_sum[3];
  float Qs = s_sq[0] + s_sq[1] + s_sq[2] + s_sq[3];
  float mu = S * (1.0f / HSZ);
  float var = Qs * (1.0f / HSZ) - mu * mu;
  float r = rsqrtf(var + 1e-12f);
  float4 g = *(const float4*)&gamma[tid * 4];
  float4 be = *(const float4*)&beta[tid * 4];
  float4 outv;
  outv.x = (v.x - mu) * r * g.x + be.x;
  outv.y = (v.y - mu) * r * g.y + be.y;
  outv.z = (v.z - mu) * r * g.z + be.z;
  outv.w = (v.w - mu) * r * g.w + be.w;
  *(float4*)&y[(size_t)row * HSZ + tid * 4] = outv;
}

// ---------------- launch ----------------
extern "C" void kernel_launch(void* const* d_in, const int* in_sizes, int n_in,
                              void* d_out, int out_size, void* d_ws,
                              size_t ws_size, hipStream_t stream) {
  const float* xs = (const float*)d_in[0];
  const int* mask = (const int*)d_in[1];
  const float* Wq = (const float*)d_in[2];
  const float* bq = (const float*)d_in[3];
  const float* Wk = (const float*)d_in[4];
  const float* bk = (const float*)d_in[5];
  const float* Wv = (const float*)d_in[6];
  const float* bv = (const float*)d_in[7];
  const float* Wo = (const float*)d_in[8];
  const float* bo = (const float*)d_in[9];
  const float* gamma = (const float*)d_in[10];
  const float* beta = (const float*)d_in[11];
  const int* rnd = (const int*)d_in[12];
  float* yout = (float*)d_out;

  char* ws = (char*)d_ws;
  const size_t SZ_XS = (size_t)M_ * HSZ * 2;       // 32 MB
  const size_t SZ_WT = (size_t)4 * HSZ * HSZ * 2;  // 8 MB
  short* xsb = (short*)ws;                         // also reused as ctx
  short* wt = (short*)(ws + SZ_XS);
  short* qbuf = (short*)(ws + SZ_XS + SZ_WT);
  short* kbuf = qbuf + (size_t)M_ * HSZ;
  short* vtb = kbuf + (size_t)M_ * HSZ;            // V^T (b,h,d,n)
  char* after = ws + SZ_XS + SZ_WT + 3 * SZ_XS;
  float* pO = (float*)(after + (1 << 20));         // 1024*4096 f32 = 16 MB
  float* pm = pO + (size_t)1024 * 4096;            // 256 KB
  float* pl = pm + (size_t)1024 * 64;              // 256 KB

  k_prep<<<9216, 256, 0, stream>>>(xs, xsb, Wq, Wk, Wv, Wo, wt);
  k_qkv<<<768, 512, 0, stream>>>(xsb, wt, bq, bk, bv, qbuf, kbuf, vtb);
  k_attn<<<4992, 256, 0, stream>>>(qbuf, kbuf, vtb, mask, rnd, xsb, pO, pm,
                                   pl);
  k_comb<<<dim3(2, H_, B_), 256, 0, stream>>>(pO, pm, pl, mask, xsb);
  k_out<<<256, 512, 0, stream>>>(xsb, wt, bo, xs, yout);
  k_ln<<<M_, 256, 0, stream>>>(yout, gamma, beta);
}

// Round 15
// 322.054 us; speedup vs baseline: 1.0672x; 1.0048x over previous
//
#include <hip/hip_runtime.h>
#include <hip/hip_bf16.h>

#define B_   4
#define N_   4096
#define HSZ  1024
#define H_   16
#define D_   64
#define NB_  64
#define R_   3
#define M_   (B_*N_)          // 16384 rows
#define NEGV (-1e4f)
#define LOG2E 1.4426950408889634f

typedef float f32x4 __attribute__((ext_vector_type(4)));
typedef short s16x8 __attribute__((ext_vector_type(8)));
typedef __bf16 b16x8 __attribute__((ext_vector_type(8)));

__device__ __forceinline__ f32x4 mfma16(s16x8 a, s16x8 b, f32x4 c) {
  return __builtin_amdgcn_mfma_f32_16x16x32_bf16(
      __builtin_bit_cast(b16x8, a), __builtin_bit_cast(b16x8, b), c, 0, 0, 0);
}

__device__ __forceinline__ short f2b(float x) {
  __hip_bfloat16 h = __float2bfloat16(x);
  return (short)__builtin_bit_cast(unsigned short, h);
}

__device__ __forceinline__ unsigned pack2(float a, float b) {
  return (unsigned)(unsigned short)f2b(a) |
         ((unsigned)(unsigned short)f2b(b) << 16);
}

// async global->LDS, 16B per lane; LDS dest = wave-uniform base + lane*16
__device__ __forceinline__ void gl_lds16(const short* g, short* l) {
  __builtin_amdgcn_global_load_lds(
      (const __attribute__((address_space(1))) unsigned int*)g,
      (__attribute__((address_space(3))) unsigned int*)l, 16, 0, 0);
}

// ---------------- fused conversions: xs->bf16 + weight transpose ----------
__global__ __launch_bounds__(256) void k_prep(const float* __restrict__ in,
                                              short* __restrict__ out,
                                              const float* __restrict__ Wq,
                                              const float* __restrict__ Wk,
                                              const float* __restrict__ Wv,
                                              const float* __restrict__ Wo,
                                              short* __restrict__ wt) {
  const int tid = threadIdx.x;
  if (blockIdx.x < 8192) {
    size_t i = ((size_t)blockIdx.x * 256 + tid) * 8;
    float4 a = *(const float4*)&in[i];
    float4 b = *(const float4*)&in[i + 4];
    s16x8 o;
    o[0] = f2b(a.x); o[1] = f2b(a.y); o[2] = f2b(a.z); o[3] = f2b(a.w);
    o[4] = f2b(b.x); o[5] = f2b(b.y); o[6] = f2b(b.z); o[7] = f2b(b.w);
    *(s16x8*)&out[i] = o;
    return;
  }
  const int bid = blockIdx.x - 8192;            // 0..1023
  const int z = bid >> 8;
  const int rest = bid & 255;
  const int tk = (rest >> 4) * 64, tn = (rest & 15) * 64;
  const float* src = (z == 0) ? Wq : (z == 1) ? Wk : (z == 2) ? Wv : Wo;
  short* dst = wt + (size_t)z * HSZ * HSZ;
  __shared__ __align__(16) float t[64][68];
#pragma unroll
  for (int r = 0; r < 4; ++r) {
    int c = tid + r * 256;
    int row = c >> 4, seg = c & 15;
    *(float4*)&t[row][seg * 4] =
        *(const float4*)&src[(size_t)(tk + row) * HSZ + tn + seg * 4];
  }
  __syncthreads();
#pragma unroll
  for (int r = 0; r < 2; ++r) {
    int c = tid + r * 256;
    int row = c >> 3, seg = c & 7;
    s16x8 o;
#pragma unroll
    for (int u = 0; u < 8; ++u) o[u] = f2b(t[seg * 8 + u][row]);
    *(s16x8*)&dst[(size_t)(tn + row) * HSZ + tk + seg * 8] = o;
  }
}

// ---------------- 256x256 8-phase GEMM core (T3+T4, pipelined ds_reads) ----
// Per phase: issue NEXT phase's A-fragment ds_reads, then MFMA current
// (latency hides under barrier + MFMA); B fragments loaded once per tile
// right after the tile-resident barrier. Staging barriers unchanged.
template <bool SWAP>
__device__ __forceinline__ void gemm8_core(
    const short* __restrict__ A, const short* __restrict__ Bt, int tm, int tn,
    short (&a_lds)[2][256][64], short (&b_lds)[2][256][64],
    f32x4 (&acc)[8][4], int wave, int lane) {
  const int lq = lane & 15, g = lane >> 4;
  const int wm = wave >> 2, wn = wave & 3;
  const int sl8 = lane >> 3;
  const int sc = ((lane & 7) ^ sl8) * 8;   // pre-swizzled global 16B slot

  auto ST_A = [&](int buf, int kt) {
#pragma unroll
    for (int h = 0; h < 2; ++h)
#pragma unroll
      for (int u = 0; u < 2; ++u) {
        const int rbase = h * 128 + wave * 8 + u * 64;
        gl_lds16(&A[(size_t)(tm + rbase + sl8) * HSZ + kt * 64 + sc],
                 &a_lds[buf][rbase][0]);
      }
  };
  auto ST_B = [&](int buf, int kt) {
#pragma unroll
    for (int h = 0; h < 2; ++h)
#pragma unroll
      for (int u = 0; u < 2; ++u) {
        const int rbase = h * 128 + wave * 8 + u * 64;
        gl_lds16(&Bt[(size_t)(tn + rbase + sl8) * HSZ + kt * 64 + sc],
                 &b_lds[buf][rbase][0]);
      }
  };

  s16x8 bf[4][2];
  auto LOADB = [&](int buf) {
#pragma unroll
    for (int j = 0; j < 4; ++j) {
      const int row = wn * 64 + j * 16 + lq;
#pragma unroll
      for (int kk = 0; kk < 2; ++kk)
        bf[j][kk] =
            *(const s16x8*)&b_lds[buf][row][((kk * 4 + g) ^ (lq & 7)) * 8];
    }
  };
  s16x8 afc[2][2], afn[2][2];
  auto LOADA = [&](int buf, int m0, s16x8 (&af)[2][2]) {
#pragma unroll
    for (int i = 0; i < 2; ++i) {
      const int row = wm * 128 + (m0 + i) * 16 + lq;
#pragma unroll
      for (int kk = 0; kk < 2; ++kk)
        af[i][kk] =
            *(const s16x8*)&a_lds[buf][row][((kk * 4 + g) ^ (lq & 7)) * 8];
    }
  };
  auto MF = [&](s16x8 (&af)[2][2], int m0) {
    __builtin_amdgcn_s_setprio(1);
#pragma unroll
    for (int i = 0; i < 2; ++i)
#pragma unroll
      for (int j = 0; j < 4; ++j)
#pragma unroll
        for (int kk = 0; kk < 2; ++kk)
          acc[m0 + i][j] = SWAP
                               ? mfma16(bf[j][kk], af[i][kk], acc[m0 + i][j])
                               : mfma16(af[i][kk], bf[j][kk], acc[m0 + i][j]);
    __builtin_amdgcn_s_setprio(0);
    __builtin_amdgcn_s_barrier();
  };

  // prologue: tile0 (A+B) + tile1 B  -> 12 loads/thread outstanding
  ST_A(0, 0);
  ST_B(0, 0);
  ST_B(1, 1);

  for (int p = 0; p < 8; ++p) {
    const int t = 2 * p;
    // ---- tile t (buf0) ----
    ST_A(1, t + 1);                               // buf1.A free since prev P7
    asm volatile("s_waitcnt vmcnt(8)" ::: "memory");  // tile t resident
    __builtin_amdgcn_s_barrier();
    LOADB(0);
    LOADA(0, 0, afc);
    LOADA(0, 2, afn);
    MF(afc, 0);                                   // P0 (+bar)
    if (t + 2 < 16) ST_B(0, t + 2);               // buf0.B free after P0 bar
    LOADA(0, 4, afc);
    MF(afn, 2);                                   // P1
    LOADA(0, 6, afn);
    MF(afc, 4);                                   // P2
    MF(afn, 6);                                   // P3 (all buf0.A reads done)
    // ---- tile t+1 (buf1) ----
    if (t + 2 < 16) ST_A(0, t + 2);               // buf0.A free after P3 bar
    if (p < 7) {
      asm volatile("s_waitcnt vmcnt(8)" ::: "memory");
    } else {
      asm volatile("s_waitcnt vmcnt(0)" ::: "memory");
    }
    __builtin_amdgcn_s_barrier();
    LOADB(1);
    LOADA(1, 0, afc);
    LOADA(1, 2, afn);
    MF(afc, 0);                                   // P4
    if (t + 3 < 16) ST_B(1, t + 3);               // buf1.B free after P4 bar
    LOADA(1, 4, afc);
    MF(afn, 2);                                   // P5
    LOADA(1, 6, afn);
    MF(afc, 4);                                   // P6
    MF(afn, 6);                                   // P7 (buf1.A reads done)
  }
}

// QKV projection: grid 768 (1D, XCD-grouped), 512 thr. z=0 Q (swapped,
// scaled), z=1 K (swapped), z=2 V (unswapped -> V^T (b,h,d,n)).
__global__ __launch_bounds__(512) void k_qkv(
    const short* __restrict__ A, const short* __restrict__ WT,
    const float* __restrict__ bq, const float* __restrict__ bk,
    const float* __restrict__ bv, short* __restrict__ oq,
    short* __restrict__ ok, short* __restrict__ ovt) {
  const int orig = blockIdx.x;                 // 0..767
  const int xcd = orig & 7, r = orig >> 3;     // r: 0..95
  const int tml = r / 12, rem = r % 12;
  const int z = rem >> 2, tnl = rem & 3;
  const int tm = (xcd * 8 + tml) * 256, tn = tnl * 256;
  const short* Bt = WT + (size_t)z * HSZ * HSZ;

  __shared__ __align__(16) short a_lds[2][256][64];
  __shared__ __align__(16) short b_lds[2][256][64];

  const int tid = threadIdx.x, lane = tid & 63, wave = tid >> 6;
  const int lq = lane & 15, g = lane >> 4;
  const int wm = wave >> 2, wn = wave & 3;

  f32x4 acc[8][4] = {};

  if (z == 2) {
    gemm8_core<false>(A, Bt, tm, tn, a_lds, b_lds, acc, wave, lane);
    // unswapped: lane holds 4 consecutive tokens (rows) for one d-col
#pragma unroll
    for (int j = 0; j < 4; ++j) {
      const int col = tn + wn * 64 + j * 16 + lq;
      const int hh = col >> 6, dd = col & 63;
      const float bi = bv[col];
#pragma unroll
      for (int i = 0; i < 8; ++i) {
        const int nrow = tm + wm * 128 + i * 16 + g * 4;
        const int bb = nrow >> 12, nn = nrow & (N_ - 1);
        uint2 w;
        w.x = pack2(acc[i][j][0] + bi, acc[i][j][1] + bi);
        w.y = pack2(acc[i][j][2] + bi, acc[i][j][3] + bi);
        *(uint2*)&ovt[(((size_t)bb * H_ + hh) * D_ + dd) * N_ + nn] = w;
      }
    }
  } else {
    gemm8_core<true>(A, Bt, tm, tn, a_lds, b_lds, acc, wave, lane);
    const float* bias = z ? bk : bq;
    short* outb = z ? ok : oq;
    const float alpha = z ? 1.0f : 0.125f * LOG2E;
    // swapped: lane holds 4 consecutive N-cols for one M-row
#pragma unroll
    for (int i = 0; i < 8; ++i) {
      const int row = tm + wm * 128 + i * 16 + lq;
#pragma unroll
      for (int j = 0; j < 4; ++j) {
        const int colb = tn + wn * 64 + j * 16 + g * 4;
        const float4 bi = *(const float4*)&bias[colb];
        const int bb = row >> 12, nn = row & (N_ - 1);
        const int hh = colb >> 6, dd = colb & 63;
        uint2 w;
        w.x = pack2((acc[i][j][0] + bi.x) * alpha,
                    (acc[i][j][1] + bi.y) * alpha);
        w.y = pack2((acc[i][j][2] + bi.z) * alpha,
                    (acc[i][j][3] + bi.w) * alpha);
        *(uint2*)&outb[(((size_t)bb * H_ + hh) * N_ + nn) * D_ + dd] = w;
      }
    }
  }
}

// Output projection: y = ctx @ Wo^T + bo + xs (f32). grid 256, 512 thr.
__global__ __launch_bounds__(512) void k_out(
    const short* __restrict__ A, const short* __restrict__ WT,
    const float* __restrict__ bo, const float* __restrict__ xs,
    float* __restrict__ yout) {
  const short* Bt = WT + (size_t)3 * HSZ * HSZ;

  __shared__ __align__(16) short a_lds[2][256][64];
  __shared__ __align__(16) short b_lds[2][256][64];

  const int tid = threadIdx.x, lane = tid & 63, wave = tid >> 6;
  const int lq = lane & 15, g = lane >> 4;
  const int wm = wave >> 2, wn = wave & 3;
  const int orig = blockIdx.x;                 // 0..255
  const int xcd = orig & 7, r = orig >> 3;     // r: 0..31
  const int tml = r >> 2, tnl = r & 3;
  const int tm = (xcd * 8 + tml) * 256, tn = tnl * 256;

  f32x4 acc[8][4] = {};
  gemm8_core<true>(A, Bt, tm, tn, a_lds, b_lds, acc, wave, lane);

#pragma unroll
  for (int i = 0; i < 8; ++i) {
    const int row = tm + wm * 128 + i * 16 + lq;
#pragma unroll
    for (int j = 0; j < 4; ++j) {
      const int colb = tn + wn * 64 + j * 16 + g * 4;
      const float4 bi = *(const float4*)&bo[colb];
      const size_t idx = (size_t)row * HSZ + colb;
      const float4 xv = *(const float4*)&xs[idx];
      float4 yv;
      yv.x = acc[i][j][0] + bi.x + xv.x;
      yv.y = acc[i][j][1] + bi.y + xv.y;
      yv.z = acc[i][j][2] + bi.z + xv.z;
      yv.w = acc[i][j][3] + bi.w + xv.w;
      *(float4*)&yout[idx] = yv;
    }
  }
}

// ---------------- BigBird block-sparse attention ----------------
// (unchanged from R14): dbuf K/V^T LDS (1 barrier/iter), ones-column
// denominator on MFMA pipe, bias as MFMA C-in, XOR swizzle, XCD grid,
// uniform-shift softmax.
__global__ __launch_bounds__(256) void k_attn(
    const short* __restrict__ Q, const short* __restrict__ K,
    const short* __restrict__ VT, const int* __restrict__ mask,
    const int* __restrict__ rnd, short* __restrict__ ctx,
    float* __restrict__ pO, float* __restrict__ pm, float* __restrict__ pl) {
  const int orig = blockIdx.x;                 // 0..4991
  const int swg = (orig & 7) * 624 + (orig >> 3);
  const int s = swg % 78;
  const int bh_i = swg / 78;                   // 0..63
  const int h = bh_i & 15, b = bh_i >> 4;
  const int tid = threadIdx.x, lane = tid & 63, wave = tid >> 6;
  const int g = lane >> 4, lq = lane & 15;

  __shared__ __align__(16) short k_lds[2][64][64];
  __shared__ __align__(16) short vt_lds[2][64][64];
  __shared__ __align__(16) short p_lds[4][16][72];
  __shared__ __align__(16) float bias_s[8][64];
  __shared__ int list_s[8];
  __shared__ int Ls;

  const bool mid = (s < 62);
  const int qb = mid ? (s + 1) : (((s - 62) >> 3) ? (NB_ - 1) : 0);

  if (tid == 0) {
    int L;
    if (!mid) {
      int chunk = (s - 62) & 7;
#pragma unroll
      for (int i = 0; i < 8; ++i) list_s[i] = chunk * 8 + i;
      L = 8;
    } else {
      const int* rp = rnd + ((size_t)h * (NB_ - 2) + (qb - 1)) * R_;
      int n;
      if (qb == 1) {
        list_s[0] = 0; list_s[1] = 1; list_s[2] = 2; list_s[3] = NB_ - 1; n = 4;
      } else if (qb == NB_ - 2) {
        list_s[0] = NB_ - 3; list_s[1] = NB_ - 2; list_s[2] = NB_ - 1;
        list_s[3] = 0; n = 4;
      } else {
        list_s[0] = qb - 1; list_s[1] = qb; list_s[2] = qb + 1;
        list_s[3] = 0; list_s[4] = NB_ - 1; n = 5;
      }
      for (int j = 0; j < R_; ++j) list_s[n + j] = rp[j];
      L = n + R_;
      for (int i = L; i < 8; ++i) list_s[i] = 0;   // keep indices safe
    }
    Ls = L;
  }

  const size_t bh = (size_t)b * H_ + h;
  const size_t qrow = bh * N_ + (size_t)qb * 64 + wave * 16 + lq;
  s16x8 qf0 = *(const s16x8*)&Q[qrow * D_ + g * 8];
  s16x8 qf1 = *(const s16x8*)&Q[qrow * D_ + 32 + g * 8];

  __syncthreads();
  const int L = Ls;

  const int r0 = tid >> 3, sg = tid & 7;     // r0: 0..31, two rows each
  const int csl = (sg ^ (r0 & 7)) * 8;       // swizzled 16B slot (write side)
  const int sw = (lq & 7);                   // read-side row XOR key

  const short* Kb = K + bh * (size_t)N_ * D_;
  const short* Vb = VT + bh * (size_t)D_ * N_;
  const int* mb = mask + (size_t)b * N_;

  // precompute bias rows for all 8 list slots
  for (int t = tid; t < 512; t += 256) {
    const int i = t >> 6, kk2 = t & 63;
    bias_s[i][kk2] =
        (1.0f - (float)mb[list_s[i] * 64 + kk2]) * (NEGV * LOG2E);
  }

  s16x8 kr0, kr1, vr0, vr1;
  {
    const int kb = list_s[0];
    const short* kp = Kb + (size_t)kb * 64 * D_;
    const short* vp = Vb + (size_t)kb * 64;
    kr0 = *(const s16x8*)&kp[(size_t)r0 * D_ + sg * 8];
    kr1 = *(const s16x8*)&kp[(size_t)(r0 + 32) * D_ + sg * 8];
    vr0 = *(const s16x8*)&vp[(size_t)r0 * N_ + sg * 8];
    vr1 = *(const s16x8*)&vp[(size_t)(r0 + 32) * N_ + sg * 8];
  }

  s16x8 ones;
#pragma unroll
  for (int u = 0; u < 8; ++u) ones[u] = (short)0x3F80;  // bf16 1.0

  f32x4 o[4] = {};
  f32x4 osum = {};
  float mshift = 0.0f;

  for (int it = 0; it < L; ++it) {
    const int buf = it & 1;
    // commit staged tile to LDS buf (XOR-swizzled), issue next tile's loads
    *(s16x8*)&k_lds[buf][r0][csl] = kr0;
    *(s16x8*)&k_lds[buf][r0 + 32][csl] = kr1;
    *(s16x8*)&vt_lds[buf][r0][csl] = vr0;
    *(s16x8*)&vt_lds[buf][r0 + 32][csl] = vr1;
    if (it + 1 < L) {
      const int kb = list_s[it + 1];
      const short* kp = Kb + (size_t)kb * 64 * D_;
      const short* vp = Vb + (size_t)kb * 64;
      kr0 = *(const s16x8*)&kp[(size_t)r0 * D_ + sg * 8];
      kr1 = *(const s16x8*)&kp[(size_t)(r0 + 32) * D_ + sg * 8];
      vr0 = *(const s16x8*)&vp[(size_t)r0 * N_ + sg * 8];
      vr1 = *(const s16x8*)&vp[(size_t)(r0 + 32) * N_ + sg * 8];
    }
    __syncthreads();  // all waves committed buf; prior buf reads are 2 iters old

    // S^T = K @ Q^T, bias preloaded as MFMA C-in (rows=keys, cols=queries)
    f32x4 st[4];
#pragma unroll
    for (int f = 0; f < 4; ++f) {
      f32x4 a0 = *(const f32x4*)&bias_s[it][f * 16 + g * 4];
      s16x8 af0 = *(const s16x8*)&k_lds[buf][f * 16 + lq][(g ^ sw) * 8];
      s16x8 af1 = *(const s16x8*)&k_lds[buf][f * 16 + lq][((4 + g) ^ sw) * 8];
      a0 = mfma16(af0, qf0, a0);
      a0 = mfma16(af1, qf1, a0);
      st[f] = a0;
    }

    // exp2 (uniform-shift online softmax; fast path while mshift==0)
    if (mshift == 0.0f) {
#pragma unroll
      for (int f = 0; f < 4; ++f)
#pragma unroll
        for (int e = 0; e < 4; ++e) st[f][e] = exp2f(st[f][e]);
    } else {
#pragma unroll
      for (int f = 0; f < 4; ++f)
#pragma unroll
        for (int e = 0; e < 4; ++e) st[f][e] = exp2f(st[f][e] - mshift);
    }

    // P rows to per-wave LDS (row = query lq, cols = keys)
#pragma unroll
    for (int f = 0; f < 4; ++f) {
      uint2 w = make_uint2(pack2(st[f][0], st[f][1]),
                           pack2(st[f][2], st[f][3]));
      *(uint2*)&p_lds[wave][lq][f * 16 + g * 4] = w;
    }

    // O += P @ V ; denominator via ones-column on the MFMA pipe
#pragma unroll
    for (int kk = 0; kk < 2; ++kk) {
      s16x8 pa = *(const s16x8*)&p_lds[wave][lq][kk * 32 + g * 8];
#pragma unroll
      for (int j = 0; j < 4; ++j) {
        s16x8 bv =
            *(const s16x8*)&vt_lds[buf][j * 16 + lq][((kk * 4 + g) ^ sw) * 8];
        o[j] = mfma16(pa, bv, o[j]);
      }
      osum = mfma16(pa, ones, osum);
    }

    // overflow guard: uniform shift (never fires on typical data)
    float om = fmaxf(fmaxf(osum[0], osum[1]), fmaxf(osum[2], osum[3]));
    if (__any(om > 16777216.0f)) {
#pragma unroll
      for (int j = 0; j < 4; ++j) o[j] *= 5.9604645e-08f;  // 2^-24
      osum *= 5.9604645e-08f;
      mshift += 24.0f;
    }
  }

  if (mid) {
    float rs[4];
#pragma unroll
    for (int e = 0; e < 4; ++e)
      rs[e] = (float)mb[qb * 64 + wave * 16 + g * 4 + e] /
              fmaxf(osum[e], 1e-30f);
    __syncthreads();  // ensure no wave still reads k_lds[0] (odd-L parity)
    short (*ost)[64] = k_lds[0];
#pragma unroll
    for (int j = 0; j < 4; ++j) {
      ost[wave * 16 + g * 4 + 0][j * 16 + lq] = f2b(o[j][0] * rs[0]);
      ost[wave * 16 + g * 4 + 1][j * 16 + lq] = f2b(o[j][1] * rs[1]);
      ost[wave * 16 + g * 4 + 2][j * 16 + lq] = f2b(o[j][2] * rs[2]);
      ost[wave * 16 + g * 4 + 3][j * 16 + lq] = f2b(o[j][3] * rs[3]);
    }
    __syncthreads();
#pragma unroll
    for (int pp = 0; pp < 2; ++pp) {
      int c = tid + pp * 256;
      int row = c >> 3, seg = c & 7;
      *(s16x8*)&ctx[((size_t)b * N_ + qb * 64 + row) * HSZ + h * D_ + seg * 8] =
          *(const s16x8*)&ost[row][seg * 8];
    }
  } else {
    const int e2 = s - 62;
    const int qsel = e2 >> 3, chunk = e2 & 7;
    const size_t eidx = (bh * 2 + qsel) * 8 + chunk;
    float* po = pO + eidx * 4096;
#pragma unroll
    for (int j = 0; j < 4; ++j)
#pragma unroll
      for (int e = 0; e < 4; ++e)
        po[(wave * 16 + g * 4 + e) * 64 + j * 16 + lq] = o[j][e];
    if (lq == 0) {
#pragma unroll
      for (int e = 0; e < 4; ++e) {
        pm[eidx * 64 + wave * 16 + g * 4 + e] = mshift;
        pl[eidx * 64 + wave * 16 + g * 4 + e] = osum[e];
      }
    }
  }
}

// ---------------- combine edge partials (log2-domain shifts) ----------------
__global__ __launch_bounds__(256) void k_comb(
    const float* __restrict__ pO, const float* __restrict__ pm,
    const float* __restrict__ pl, const int* __restrict__ mask,
    short* __restrict__ ctx) {
  const int qsel = blockIdx.x, h = blockIdx.y, b = blockIdx.z;
  const int qb = qsel ? NB_ - 1 : 0;
  const int tid = threadIdx.x;
  const int q = tid >> 2, dq = tid & 3;
  const size_t base = (((size_t)b * H_ + h) * 2 + qsel) * 8;

  float mv[8];
  float M = -INFINITY;
#pragma unroll
  for (int i = 0; i < 8; ++i) {
    mv[i] = pm[(base + i) * 64 + q];
    M = fmaxf(M, mv[i]);
  }
  float Lsum = 0.0f;
#pragma unroll
  for (int i = 0; i < 8; ++i) {
    float w = exp2f(mv[i] - M);
    mv[i] = w;
    Lsum += pl[(base + i) * 64 + q] * w;
  }
  f32x4 acc[4] = {};
#pragma unroll
  for (int i = 0; i < 8; ++i) {
    const float* p = pO + (base + i) * 4096 + q * 64 + dq * 16;
    float w = mv[i];
#pragma unroll
    for (int u = 0; u < 4; ++u) {
      f32x4 v = *(const f32x4*)&p[u * 4];
      acc[u] += v * w;
    }
  }
  float sc = (float)mask[(size_t)b * N_ + qb * 64 + q] / fmaxf(Lsum, 1e-30f);
  s16x8 out0, out1;
#pragma unroll
  for (int u = 0; u < 8; ++u) {
    out0[u] = f2b(acc[u >> 2][u & 3] * sc);
    out1[u] = f2b(acc[2 + (u >> 2)][u & 3] * sc);
  }
  short* dst = &ctx[((size_t)b * N_ + qb * 64 + q) * HSZ + h * D_ + dq * 16];
  *(s16x8*)dst = out0;
  *(s16x8*)(dst + 8) = out1;
}

// ---------------- LayerNorm (in place on y) ----------------
__global__ __launch_bounds__(256) void k_ln(float* __restrict__ y,
                                            const float* __restrict__ gamma,
                                            const float* __restrict__ beta) {
  const int row = blockIdx.x, tid = threadIdx.x, lane = tid & 63,
            wave = tid >> 6;
  __shared__ float s_sum[4], s_sq[4];
  float4 v = *(const float4*)&y[(size_t)row * HSZ + tid * 4];
  float s = v.x + v.y + v.z + v.w;
  float q = v.x * v.x + v.y * v.y + v.z * v.z + v.w * v.w;
#pragma unroll
  for (int m = 1; m <= 32; m <<= 1) {
    s += __shfl_xor(s, m);
    q += __shfl_xor(q, m);
  }
  if (lane == 0) { s_sum[wave] = s; s_sq[wave] = q; }
  __syncthreads();
  float S = s_sum[0] + s_sum[1] + s_sum[2] + s_sum[3];
  float Qs = s_sq[0] + s_sq[1] + s_sq[2] + s_sq[3];
  float mu = S * (1.0f / HSZ);
  float var = Qs * (1.0f / HSZ) - mu * mu;
  float r = rsqrtf(var + 1e-12f);
  float4 g = *(const float4*)&gamma[tid * 4];
  float4 be = *(const float4*)&beta[tid * 4];
  float4 outv;
  outv.x = (v.x - mu) * r * g.x + be.x;
  outv.y = (v.y - mu) * r * g.y + be.y;
  outv.z = (v.z - mu) * r * g.z + be.z;
  outv.w = (v.w - mu) * r * g.w + be.w;
  *(float4*)&y[(size_t)row * HSZ + tid * 4] = outv;
}

// ---------------- launch ----------------
extern "C" void kernel_launch(void* const* d_in, const int* in_sizes, int n_in,
                              void* d_out, int out_size, void* d_ws,
                              size_t ws_size, hipStream_t stream) {
  const float* xs = (const float*)d_in[0];
  const int* mask = (const int*)d_in[1];
  const float* Wq = (const float*)d_in[2];
  const float* bq = (const float*)d_in[3];
  const float* Wk = (const float*)d_in[4];
  const float* bk = (const float*)d_in[5];
  const float* Wv = (const float*)d_in[6];
  const float* bv = (const float*)d_in[7];
  const float* Wo = (const float*)d_in[8];
  const float* bo = (const float*)d_in[9];
  const float* gamma = (const float*)d_in[10];
  const float* beta = (const float*)d_in[11];
  const int* rnd = (const int*)d_in[12];
  float* yout = (float*)d_out;

  char* ws = (char*)d_ws;
  const size_t SZ_XS = (size_t)M_ * HSZ * 2;       // 32 MB
  const size_t SZ_WT = (size_t)4 * HSZ * HSZ * 2;  // 8 MB
  short* xsb = (short*)ws;                         // also reused as ctx
  short* wt = (short*)(ws + SZ_XS);
  short* qbuf = (short*)(ws + SZ_XS + SZ_WT);
  short* kbuf = qbuf + (size_t)M_ * HSZ;
  short* vtb = kbuf + (size_t)M_ * HSZ;            // V^T (b,h,d,n)
  char* after = ws + SZ_XS + SZ_WT + 3 * SZ_XS;
  float* pO = (float*)(after + (1 << 20));         // 1024*4096 f32 = 16 MB
  float* pm = pO + (size_t)1024 * 4096;            // 256 KB
  float* pl = pm + (size_t)1024 * 64;              // 256 KB

  k_prep<<<9216, 256, 0, stream>>>(xs, xsb, Wq, Wk, Wv, Wo, wt);
  k_qkv<<<768, 512, 0, stream>>>(xsb, wt, bq, bk, bv, qbuf, kbuf, vtb);
  k_attn<<<4992, 256, 0, stream>>>(qbuf, kbuf, vtb, mask, rnd, xsb, pO, pm,
                                   pl);
  k_comb<<<dim3(2, H_, B_), 256, 0, stream>>>(pO, pm, pl, mask, xsb);
  k_out<<<256, 512, 0, stream>>>(xsb, wt, bo, xs, yout);
  k_ln<<<M_, 256, 0, stream>>>(yout, gamma, beta);
}

// Round 16
// 316.953 us; speedup vs baseline: 1.0844x; 1.0161x over previous
//
#include <hip/hip_runtime.h>
#include <hip/hip_bf16.h>

#define B_   4
#define N_   4096
#define HSZ  1024
#define H_   16
#define D_   64
#define NB_  64
#define R_   3
#define M_   (B_*N_)          // 16384 rows
#define NEGV (-1e4f)
#define LOG2E 1.4426950408889634f

typedef float f32x4 __attribute__((ext_vector_type(4)));
typedef short s16x8 __attribute__((ext_vector_type(8)));
typedef __bf16 b16x8 __attribute__((ext_vector_type(8)));

__device__ __forceinline__ f32x4 mfma16(s16x8 a, s16x8 b, f32x4 c) {
  return __builtin_amdgcn_mfma_f32_16x16x32_bf16(
      __builtin_bit_cast(b16x8, a), __builtin_bit_cast(b16x8, b), c, 0, 0, 0);
}

__device__ __forceinline__ short f2b(float x) {
  __hip_bfloat16 h = __float2bfloat16(x);
  return (short)__builtin_bit_cast(unsigned short, h);
}

__device__ __forceinline__ unsigned pack2(float a, float b) {
  return (unsigned)(unsigned short)f2b(a) |
         ((unsigned)(unsigned short)f2b(b) << 16);
}

// async global->LDS, 16B per lane; LDS dest = wave-uniform base + lane*16
__device__ __forceinline__ void gl_lds16(const short* g, short* l) {
  __builtin_amdgcn_global_load_lds(
      (const __attribute__((address_space(1))) unsigned int*)g,
      (__attribute__((address_space(3))) unsigned int*)l, 16, 0, 0);
}

// ---------------- fused conversions: xs->bf16 + weight transpose ----------
__global__ __launch_bounds__(256) void k_prep(const float* __restrict__ in,
                                              short* __restrict__ out,
                                              const float* __restrict__ Wq,
                                              const float* __restrict__ Wk,
                                              const float* __restrict__ Wv,
                                              const float* __restrict__ Wo,
                                              short* __restrict__ wt) {
  const int tid = threadIdx.x;
  if (blockIdx.x < 8192) {
    size_t i = ((size_t)blockIdx.x * 256 + tid) * 8;
    float4 a = *(const float4*)&in[i];
    float4 b = *(const float4*)&in[i + 4];
    s16x8 o;
    o[0] = f2b(a.x); o[1] = f2b(a.y); o[2] = f2b(a.z); o[3] = f2b(a.w);
    o[4] = f2b(b.x); o[5] = f2b(b.y); o[6] = f2b(b.z); o[7] = f2b(b.w);
    *(s16x8*)&out[i] = o;
    return;
  }
  const int bid = blockIdx.x - 8192;            // 0..1023
  const int z = bid >> 8;
  const int rest = bid & 255;
  const int tk = (rest >> 4) * 64, tn = (rest & 15) * 64;
  const float* src = (z == 0) ? Wq : (z == 1) ? Wk : (z == 2) ? Wv : Wo;
  short* dst = wt + (size_t)z * HSZ * HSZ;
  __shared__ __align__(16) float t[64][68];
#pragma unroll
  for (int r = 0; r < 4; ++r) {
    int c = tid + r * 256;
    int row = c >> 4, seg = c & 15;
    *(float4*)&t[row][seg * 4] =
        *(const float4*)&src[(size_t)(tk + row) * HSZ + tn + seg * 4];
  }
  __syncthreads();
#pragma unroll
  for (int r = 0; r < 2; ++r) {
    int c = tid + r * 256;
    int row = c >> 3, seg = c & 7;
    s16x8 o;
#pragma unroll
    for (int u = 0; u < 8; ++u) o[u] = f2b(t[seg * 8 + u][row]);
    *(s16x8*)&dst[(size_t)(tn + row) * HSZ + tk + seg * 8] = o;
  }
}

// ---------------- 256x256 8-phase GEMM core (T3+T4, pipelined ds_reads) ----
template <bool SWAP>
__device__ __forceinline__ void gemm8_core(
    const short* __restrict__ A, const short* __restrict__ Bt, int tm, int tn,
    short (&a_lds)[2][256][64], short (&b_lds)[2][256][64],
    f32x4 (&acc)[8][4], int wave, int lane) {
  const int lq = lane & 15, g = lane >> 4;
  const int wm = wave >> 2, wn = wave & 3;
  const int sl8 = lane >> 3;
  const int sc = ((lane & 7) ^ sl8) * 8;   // pre-swizzled global 16B slot

  auto ST_A = [&](int buf, int kt) {
#pragma unroll
    for (int h = 0; h < 2; ++h)
#pragma unroll
      for (int u = 0; u < 2; ++u) {
        const int rbase = h * 128 + wave * 8 + u * 64;
        gl_lds16(&A[(size_t)(tm + rbase + sl8) * HSZ + kt * 64 + sc],
                 &a_lds[buf][rbase][0]);
      }
  };
  auto ST_B = [&](int buf, int kt) {
#pragma unroll
    for (int h = 0; h < 2; ++h)
#pragma unroll
      for (int u = 0; u < 2; ++u) {
        const int rbase = h * 128 + wave * 8 + u * 64;
        gl_lds16(&Bt[(size_t)(tn + rbase + sl8) * HSZ + kt * 64 + sc],
                 &b_lds[buf][rbase][0]);
      }
  };

  s16x8 bf[4][2];
  auto LOADB = [&](int buf) {
#pragma unroll
    for (int j = 0; j < 4; ++j) {
      const int row = wn * 64 + j * 16 + lq;
#pragma unroll
      for (int kk = 0; kk < 2; ++kk)
        bf[j][kk] =
            *(const s16x8*)&b_lds[buf][row][((kk * 4 + g) ^ (lq & 7)) * 8];
    }
  };
  s16x8 afc[2][2], afn[2][2];
  auto LOADA = [&](int buf, int m0, s16x8 (&af)[2][2]) {
#pragma unroll
    for (int i = 0; i < 2; ++i) {
      const int row = wm * 128 + (m0 + i) * 16 + lq;
#pragma unroll
      for (int kk = 0; kk < 2; ++kk)
        af[i][kk] =
            *(const s16x8*)&a_lds[buf][row][((kk * 4 + g) ^ (lq & 7)) * 8];
    }
  };
  auto MF = [&](s16x8 (&af)[2][2], int m0) {
    __builtin_amdgcn_s_setprio(1);
#pragma unroll
    for (int i = 0; i < 2; ++i)
#pragma unroll
      for (int j = 0; j < 4; ++j)
#pragma unroll
        for (int kk = 0; kk < 2; ++kk)
          acc[m0 + i][j] = SWAP
                               ? mfma16(bf[j][kk], af[i][kk], acc[m0 + i][j])
                               : mfma16(af[i][kk], bf[j][kk], acc[m0 + i][j]);
    __builtin_amdgcn_s_setprio(0);
    __builtin_amdgcn_s_barrier();
  };

  // prologue: tile0 (A+B) + tile1 B  -> 12 loads/thread outstanding
  ST_A(0, 0);
  ST_B(0, 0);
  ST_B(1, 1);

  for (int p = 0; p < 8; ++p) {
    const int t = 2 * p;
    // ---- tile t (buf0) ----
    ST_A(1, t + 1);                               // buf1.A free since prev P7
    asm volatile("s_waitcnt vmcnt(8)" ::: "memory");  // tile t resident
    __builtin_amdgcn_s_barrier();
    LOADB(0);
    LOADA(0, 0, afc);
    LOADA(0, 2, afn);
    MF(afc, 0);                                   // P0 (+bar)
    if (t + 2 < 16) ST_B(0, t + 2);               // buf0.B free after P0 bar
    LOADA(0, 4, afc);
    MF(afn, 2);                                   // P1
    LOADA(0, 6, afn);
    MF(afc, 4);                                   // P2
    MF(afn, 6);                                   // P3 (all buf0.A reads done)
    // ---- tile t+1 (buf1) ----
    if (t + 2 < 16) ST_A(0, t + 2);               // buf0.A free after P3 bar
    if (p < 7) {
      asm volatile("s_waitcnt vmcnt(8)" ::: "memory");
    } else {
      asm volatile("s_waitcnt vmcnt(0)" ::: "memory");
    }
    __builtin_amdgcn_s_barrier();
    LOADB(1);
    LOADA(1, 0, afc);
    LOADA(1, 2, afn);
    MF(afc, 0);                                   // P4
    if (t + 3 < 16) ST_B(1, t + 3);               // buf1.B free after P4 bar
    LOADA(1, 4, afc);
    MF(afn, 2);                                   // P5
    LOADA(1, 6, afn);
    MF(afc, 4);                                   // P6
    MF(afn, 6);                                   // P7 (buf1.A reads done)
  }
}

// QKV projection: grid 768 (1D, XCD-grouped), 512 thr.
// (z,tn)-major per XCD: each XCD keeps one 512 KB weight slice L2-hot across
// 8 consecutive M-panels; A panel re-reads hit L3.
__global__ __launch_bounds__(512) void k_qkv(
    const short* __restrict__ A, const short* __restrict__ WT,
    const float* __restrict__ bq, const float* __restrict__ bk,
    const float* __restrict__ bv, short* __restrict__ oq,
    short* __restrict__ ok, short* __restrict__ ovt) {
  const int orig = blockIdx.x;                 // 0..767
  const int xcd = orig & 7, r = orig >> 3;     // r: 0..95
  const int combo = r >> 3, tml = r & 7;       // combo: 0..11
  const int z = combo >> 2, tnl = combo & 3;
  const int tm = (xcd * 8 + tml) * 256, tn = tnl * 256;
  const short* Bt = WT + (size_t)z * HSZ * HSZ;

  __shared__ __align__(16) short a_lds[2][256][64];
  __shared__ __align__(16) short b_lds[2][256][64];

  const int tid = threadIdx.x, lane = tid & 63, wave = tid >> 6;
  const int lq = lane & 15, g = lane >> 4;
  const int wm = wave >> 2, wn = wave & 3;

  f32x4 acc[8][4] = {};

  if (z == 2) {
    gemm8_core<false>(A, Bt, tm, tn, a_lds, b_lds, acc, wave, lane);
    // unswapped: lane holds 4 consecutive tokens (rows) for one d-col
#pragma unroll
    for (int j = 0; j < 4; ++j) {
      const int col = tn + wn * 64 + j * 16 + lq;
      const int hh = col >> 6, dd = col & 63;
      const float bi = bv[col];
#pragma unroll
      for (int i = 0; i < 8; ++i) {
        const int nrow = tm + wm * 128 + i * 16 + g * 4;
        const int bb = nrow >> 12, nn = nrow & (N_ - 1);
        uint2 w;
        w.x = pack2(acc[i][j][0] + bi, acc[i][j][1] + bi);
        w.y = pack2(acc[i][j][2] + bi, acc[i][j][3] + bi);
        *(uint2*)&ovt[(((size_t)bb * H_ + hh) * D_ + dd) * N_ + nn] = w;
      }
    }
  } else {
    gemm8_core<true>(A, Bt, tm, tn, a_lds, b_lds, acc, wave, lane);
    const float* bias = z ? bk : bq;
    short* outb = z ? ok : oq;
    const float alpha = z ? 1.0f : 0.125f * LOG2E;
    // swapped: lane holds 4 consecutive N-cols for one M-row
#pragma unroll
    for (int i = 0; i < 8; ++i) {
      const int row = tm + wm * 128 + i * 16 + lq;
#pragma unroll
      for (int j = 0; j < 4; ++j) {
        const int colb = tn + wn * 64 + j * 16 + g * 4;
        const float4 bi = *(const float4*)&bias[colb];
        const int bb = row >> 12, nn = row & (N_ - 1);
        const int hh = colb >> 6, dd = colb & 63;
        uint2 w;
        w.x = pack2((acc[i][j][0] + bi.x) * alpha,
                    (acc[i][j][1] + bi.y) * alpha);
        w.y = pack2((acc[i][j][2] + bi.z) * alpha,
                    (acc[i][j][3] + bi.w) * alpha);
        *(uint2*)&outb[(((size_t)bb * H_ + hh) * N_ + nn) * D_ + dd] = w;
      }
    }
  }
}

// Output projection: y = ctx @ Wo^T + bo + xs (f32). grid 256, 512 thr.
// tn-major per XCD (weight slice L2-resident).
__global__ __launch_bounds__(512) void k_out(
    const short* __restrict__ A, const short* __restrict__ WT,
    const float* __restrict__ bo, const float* __restrict__ xs,
    float* __restrict__ yout) {
  const short* Bt = WT + (size_t)3 * HSZ * HSZ;

  __shared__ __align__(16) short a_lds[2][256][64];
  __shared__ __align__(16) short b_lds[2][256][64];

  const int tid = threadIdx.x, lane = tid & 63, wave = tid >> 6;
  const int lq = lane & 15, g = lane >> 4;
  const int wm = wave >> 2, wn = wave & 3;
  const int orig = blockIdx.x;                 // 0..255
  const int xcd = orig & 7, r = orig >> 3;     // r: 0..31
  const int tnl = r >> 3, tml = r & 7;
  const int tm = (xcd * 8 + tml) * 256, tn = tnl * 256;

  f32x4 acc[8][4] = {};
  gemm8_core<true>(A, Bt, tm, tn, a_lds, b_lds, acc, wave, lane);

#pragma unroll
  for (int i = 0; i < 8; ++i) {
    const int row = tm + wm * 128 + i * 16 + lq;
#pragma unroll
    for (int j = 0; j < 4; ++j) {
      const int colb = tn + wn * 64 + j * 16 + g * 4;
      const float4 bi = *(const float4*)&bo[colb];
      const size_t idx = (size_t)row * HSZ + colb;
      const float4 xv = *(const float4*)&xs[idx];
      float4 yv;
      yv.x = acc[i][j][0] + bi.x + xv.x;
      yv.y = acc[i][j][1] + bi.y + xv.y;
      yv.z = acc[i][j][2] + bi.z + xv.z;
      yv.w = acc[i][j][3] + bi.w + xv.w;
      *(float4*)&yout[idx] = yv;
    }
  }
}

// ---------------- BigBird block-sparse attention ----------------
// (unchanged from R15): dbuf K/V^T LDS (1 barrier/iter), ones-column
// denominator on MFMA pipe, bias as MFMA C-in, XOR swizzle, XCD grid,
// uniform-shift softmax.
__global__ __launch_bounds__(256) void k_attn(
    const short* __restrict__ Q, const short* __restrict__ K,
    const short* __restrict__ VT, const int* __restrict__ mask,
    const int* __restrict__ rnd, short* __restrict__ ctx,
    float* __restrict__ pO, float* __restrict__ pm, float* __restrict__ pl) {
  const int orig = blockIdx.x;                 // 0..4991
  const int swg = (orig & 7) * 624 + (orig >> 3);
  const int s = swg % 78;
  const int bh_i = swg / 78;                   // 0..63
  const int h = bh_i & 15, b = bh_i >> 4;
  const int tid = threadIdx.x, lane = tid & 63, wave = tid >> 6;
  const int g = lane >> 4, lq = lane & 15;

  __shared__ __align__(16) short k_lds[2][64][64];
  __shared__ __align__(16) short vt_lds[2][64][64];
  __shared__ __align__(16) short p_lds[4][16][72];
  __shared__ __align__(16) float bias_s[8][64];
  __shared__ int list_s[8];
  __shared__ int Ls;

  const bool mid = (s < 62);
  const int qb = mid ? (s + 1) : (((s - 62) >> 3) ? (NB_ - 1) : 0);

  if (tid == 0) {
    int L;
    if (!mid) {
      int chunk = (s - 62) & 7;
#pragma unroll
      for (int i = 0; i < 8; ++i) list_s[i] = chunk * 8 + i;
      L = 8;
    } else {
      const int* rp = rnd + ((size_t)h * (NB_ - 2) + (qb - 1)) * R_;
      int n;
      if (qb == 1) {
        list_s[0] = 0; list_s[1] = 1; list_s[2] = 2; list_s[3] = NB_ - 1; n = 4;
      } else if (qb == NB_ - 2) {
        list_s[0] = NB_ - 3; list_s[1] = NB_ - 2; list_s[2] = NB_ - 1;
        list_s[3] = 0; n = 4;
      } else {
        list_s[0] = qb - 1; list_s[1] = qb; list_s[2] = qb + 1;
        list_s[3] = 0; list_s[4] = NB_ - 1; n = 5;
      }
      for (int j = 0; j < R_; ++j) list_s[n + j] = rp[j];
      L = n + R_;
      for (int i = L; i < 8; ++i) list_s[i] = 0;   // keep indices safe
    }
    Ls = L;
  }

  const size_t bh = (size_t)b * H_ + h;
  const size_t qrow = bh * N_ + (size_t)qb * 64 + wave * 16 + lq;
  s16x8 qf0 = *(const s16x8*)&Q[qrow * D_ + g * 8];
  s16x8 qf1 = *(const s16x8*)&Q[qrow * D_ + 32 + g * 8];

  __syncthreads();
  const int L = Ls;

  const int r0 = tid >> 3, sg = tid & 7;     // r0: 0..31, two rows each
  const int csl = (sg ^ (r0 & 7)) * 8;       // swizzled 16B slot (write side)
  const int sw = (lq & 7);                   // read-side row XOR key

  const short* Kb = K + bh * (size_t)N_ * D_;
  const short* Vb = VT + bh * (size_t)D_ * N_;
  const int* mb = mask + (size_t)b * N_;

  // precompute bias rows for all 8 list slots
  for (int t = tid; t < 512; t += 256) {
    const int i = t >> 6, kk2 = t & 63;
    bias_s[i][kk2] =
        (1.0f - (float)mb[list_s[i] * 64 + kk2]) * (NEGV * LOG2E);
  }

  s16x8 kr0, kr1, vr0, vr1;
  {
    const int kb = list_s[0];
    const short* kp = Kb + (size_t)kb * 64 * D_;
    const short* vp = Vb + (size_t)kb * 64;
    kr0 = *(const s16x8*)&kp[(size_t)r0 * D_ + sg * 8];
    kr1 = *(const s16x8*)&kp[(size_t)(r0 + 32) * D_ + sg * 8];
    vr0 = *(const s16x8*)&vp[(size_t)r0 * N_ + sg * 8];
    vr1 = *(const s16x8*)&vp[(size_t)(r0 + 32) * N_ + sg * 8];
  }

  s16x8 ones;
#pragma unroll
  for (int u = 0; u < 8; ++u) ones[u] = (short)0x3F80;  // bf16 1.0

  f32x4 o[4] = {};
  f32x4 osum = {};
  float mshift = 0.0f;

  for (int it = 0; it < L; ++it) {
    const int buf = it & 1;
    // commit staged tile to LDS buf (XOR-swizzled), issue next tile's loads
    *(s16x8*)&k_lds[buf][r0][csl] = kr0;
    *(s16x8*)&k_lds[buf][r0 + 32][csl] = kr1;
    *(s16x8*)&vt_lds[buf][r0][csl] = vr0;
    *(s16x8*)&vt_lds[buf][r0 + 32][csl] = vr1;
    if (it + 1 < L) {
      const int kb = list_s[it + 1];
      const short* kp = Kb + (size_t)kb * 64 * D_;
      const short* vp = Vb + (size_t)kb * 64;
      kr0 = *(const s16x8*)&kp[(size_t)r0 * D_ + sg * 8];
      kr1 = *(const s16x8*)&kp[(size_t)(r0 + 32) * D_ + sg * 8];
      vr0 = *(const s16x8*)&vp[(size_t)r0 * N_ + sg * 8];
      vr1 = *(const s16x8*)&vp[(size_t)(r0 + 32) * N_ + sg * 8];
    }
    __syncthreads();  // all waves committed buf; prior buf reads are 2 iters old

    // S^T = K @ Q^T, bias preloaded as MFMA C-in (rows=keys, cols=queries)
    f32x4 st[4];
#pragma unroll
    for (int f = 0; f < 4; ++f) {
      f32x4 a0 = *(const f32x4*)&bias_s[it][f * 16 + g * 4];
      s16x8 af0 = *(const s16x8*)&k_lds[buf][f * 16 + lq][(g ^ sw) * 8];
      s16x8 af1 = *(const s16x8*)&k_lds[buf][f * 16 + lq][((4 + g) ^ sw) * 8];
      a0 = mfma16(af0, qf0, a0);
      a0 = mfma16(af1, qf1, a0);
      st[f] = a0;
    }

    // exp2 (uniform-shift online softmax; fast path while mshift==0)
    if (mshift == 0.0f) {
#pragma unroll
      for (int f = 0; f < 4; ++f)
#pragma unroll
        for (int e = 0; e < 4; ++e) st[f][e] = exp2f(st[f][e]);
    } else {
#pragma unroll
      for (int f = 0; f < 4; ++f)
#pragma unroll
        for (int e = 0; e < 4; ++e) st[f][e] = exp2f(st[f][e] - mshift);
    }

    // P rows to per-wave LDS (row = query lq, cols = keys)
#pragma unroll
    for (int f = 0; f < 4; ++f) {
      uint2 w = make_uint2(pack2(st[f][0], st[f][1]),
                           pack2(st[f][2], st[f][3]));
      *(uint2*)&p_lds[wave][lq][f * 16 + g * 4] = w;
    }

    // O += P @ V ; denominator via ones-column on the MFMA pipe
#pragma unroll
    for (int kk = 0; kk < 2; ++kk) {
      s16x8 pa = *(const s16x8*)&p_lds[wave][lq][kk * 32 + g * 8];
#pragma unroll
      for (int j = 0; j < 4; ++j) {
        s16x8 bv =
            *(const s16x8*)&vt_lds[buf][j * 16 + lq][((kk * 4 + g) ^ sw) * 8];
        o[j] = mfma16(pa, bv, o[j]);
      }
      osum = mfma16(pa, ones, osum);
    }

    // overflow guard: uniform shift (never fires on typical data)
    float om = fmaxf(fmaxf(osum[0], osum[1]), fmaxf(osum[2], osum[3]));
    if (__any(om > 16777216.0f)) {
#pragma unroll
      for (int j = 0; j < 4; ++j) o[j] *= 5.9604645e-08f;  // 2^-24
      osum *= 5.9604645e-08f;
      mshift += 24.0f;
    }
  }

  if (mid) {
    float rs[4];
#pragma unroll
    for (int e = 0; e < 4; ++e)
      rs[e] = (float)mb[qb * 64 + wave * 16 + g * 4 + e] /
              fmaxf(osum[e], 1e-30f);
    __syncthreads();  // ensure no wave still reads k_lds[0] (odd-L parity)
    short (*ost)[64] = k_lds[0];
#pragma unroll
    for (int j = 0; j < 4; ++j) {
      ost[wave * 16 + g * 4 + 0][j * 16 + lq] = f2b(o[j][0] * rs[0]);
      ost[wave * 16 + g * 4 + 1][j * 16 + lq] = f2b(o[j][1] * rs[1]);
      ost[wave * 16 + g * 4 + 2][j * 16 + lq] = f2b(o[j][2] * rs[2]);
      ost[wave * 16 + g * 4 + 3][j * 16 + lq] = f2b(o[j][3] * rs[3]);
    }
    __syncthreads();
#pragma unroll
    for (int pp = 0; pp < 2; ++pp) {
      int c = tid + pp * 256;
      int row = c >> 3, seg = c & 7;
      *(s16x8*)&ctx[((size_t)b * N_ + qb * 64 + row) * HSZ + h * D_ + seg * 8] =
          *(const s16x8*)&ost[row][seg * 8];
    }
  } else {
    const int e2 = s - 62;
    const int qsel = e2 >> 3, chunk = e2 & 7;
    const size_t eidx = (bh * 2 + qsel) * 8 + chunk;
    float* po = pO + eidx * 4096;
#pragma unroll
    for (int j = 0; j < 4; ++j)
#pragma unroll
      for (int e = 0; e < 4; ++e)
        po[(wave * 16 + g * 4 + e) * 64 + j * 16 + lq] = o[j][e];
    if (lq == 0) {
#pragma unroll
      for (int e = 0; e < 4; ++e) {
        pm[eidx * 64 + wave * 16 + g * 4 + e] = mshift;
        pl[eidx * 64 + wave * 16 + g * 4 + e] = osum[e];
      }
    }
  }
}

// ---------------- combine edge partials (log2-domain shifts) ----------------
__global__ __launch_bounds__(256) void k_comb(
    const float* __restrict__ pO, const float* __restrict__ pm,
    const float* __restrict__ pl, const int* __restrict__ mask,
    short* __restrict__ ctx) {
  const int qsel = blockIdx.x, h = blockIdx.y, b = blockIdx.z;
  const int qb = qsel ? NB_ - 1 : 0;
  const int tid = threadIdx.x;
  const int q = tid >> 2, dq = tid & 3;
  const size_t base = (((size_t)b * H_ + h) * 2 + qsel) * 8;

  float mv[8];
  float M = -INFINITY;
#pragma unroll
  for (int i = 0; i < 8; ++i) {
    mv[i] = pm[(base + i) * 64 + q];
    M = fmaxf(M, mv[i]);
  }
  float Lsum = 0.0f;
#pragma unroll
  for (int i = 0; i < 8; ++i) {
    float w = exp2f(mv[i] - M);
    mv[i] = w;
    Lsum += pl[(base + i) * 64 + q] * w;
  }
  f32x4 acc[4] = {};
#pragma unroll
  for (int i = 0; i < 8; ++i) {
    const float* p = pO + (base + i) * 4096 + q * 64 + dq * 16;
    float w = mv[i];
#pragma unroll
    for (int u = 0; u < 4; ++u) {
      f32x4 v = *(const f32x4*)&p[u * 4];
      acc[u] += v * w;
    }
  }
  float sc = (float)mask[(size_t)b * N_ + qb * 64 + q] / fmaxf(Lsum, 1e-30f);
  s16x8 out0, out1;
#pragma unroll
  for (int u = 0; u < 8; ++u) {
    out0[u] = f2b(acc[u >> 2][u & 3] * sc);
    out1[u] = f2b(acc[2 + (u >> 2)][u & 3] * sc);
  }
  short* dst = &ctx[((size_t)b * N_ + qb * 64 + q) * HSZ + h * D_ + dq * 16];
  *(s16x8*)dst = out0;
  *(s16x8*)(dst + 8) = out1;
}

// ---------------- LayerNorm (in place on y) ----------------
__global__ __launch_bounds__(256) void k_ln(float* __restrict__ y,
                                            const float* __restrict__ gamma,
                                            const float* __restrict__ beta) {
  const int row = blockIdx.x, tid = threadIdx.x, lane = tid & 63,
            wave = tid >> 6;
  __shared__ float s_sum[4], s_sq[4];
  float4 v = *(const float4*)&y[(size_t)row * HSZ + tid * 4];
  float s = v.x + v.y + v.z + v.w;
  float q = v.x * v.x + v.y * v.y + v.z * v.z + v.w * v.w;
#pragma unroll
  for (int m = 1; m <= 32; m <<= 1) {
    s += __shfl_xor(s, m);
    q += __shfl_xor(q, m);
  }
  if (lane == 0) { s_sum[wave] = s; s_sq[wave] = q; }
  __syncthreads();
  float S = s_sum[0] + s_sum[1] + s_sum[2] + s_sum[3];
  float Qs = s_sq[0] + s_sq[1] + s_sq[2] + s_sq[3];
  float mu = S * (1.0f / HSZ);
  float var = Qs * (1.0f / HSZ) - mu * mu;
  float r = rsqrtf(var + 1e-12f);
  float4 g = *(const float4*)&gamma[tid * 4];
  float4 be = *(const float4*)&beta[tid * 4];
  float4 outv;
  outv.x = (v.x - mu) * r * g.x + be.x;
  outv.y = (v.y - mu) * r * g.y + be.y;
  outv.z = (v.z - mu) * r * g.z + be.z;
  outv.w = (v.w - mu) * r * g.w + be.w;
  *(float4*)&y[(size_t)row * HSZ + tid * 4] = outv;
}

// ---------------- launch ----------------
extern "C" void kernel_launch(void* const* d_in, const int* in_sizes, int n_in,
                              void* d_out, int out_size, void* d_ws,
                              size_t ws_size, hipStream_t stream) {
  const float* xs = (const float*)d_in[0];
  const int* mask = (const int*)d_in[1];
  const float* Wq = (const float*)d_in[2];
  const float* bq = (const float*)d_in[3];
  const float* Wk = (const float*)d_in[4];
  const float* bk = (const float*)d_in[5];
  const float* Wv = (const float*)d_in[6];
  const float* bv = (const float*)d_in[7];
  const float* Wo = (const float*)d_in[8];
  const float* bo = (const float*)d_in[9];
  const float* gamma = (const float*)d_in[10];
  const float* beta = (const float*)d_in[11];
  const int* rnd = (const int*)d_in[12];
  float* yout = (float*)d_out;

  char* ws = (char*)d_ws;
  const size_t SZ_XS = (size_t)M_ * HSZ * 2;       // 32 MB
  const size_t SZ_WT = (size_t)4 * HSZ * HSZ * 2;  // 8 MB
  short* xsb = (short*)ws;                         // also reused as ctx
  short* wt = (short*)(ws + SZ_XS);
  short* qbuf = (short*)(ws + SZ_XS + SZ_WT);
  short* kbuf = qbuf + (size_t)M_ * HSZ;
  short* vtb = kbuf + (size_t)M_ * HSZ;            // V^T (b,h,d,n)
  char* after = ws + SZ_XS + SZ_WT + 3 * SZ_XS;
  float* pO = (float*)(after + (1 << 20));         // 1024*4096 f32 = 16 MB
  float* pm = pO + (size_t)1024 * 4096;            // 256 KB
  float* pl = pm + (size_t)1024 * 64;              // 256 KB

  k_prep<<<9216, 256, 0, stream>>>(xs, xsb, Wq, Wk, Wv, Wo, wt);
  k_qkv<<<768, 512, 0, stream>>>(xsb, wt, bq, bk, bv, qbuf, kbuf, vtb);
  k_attn<<<4992, 256, 0, stream>>>(qbuf, kbuf, vtb, mask, rnd, xsb, pO, pm,
                                   pl);
  k_comb<<<dim3(2, H_, B_), 256, 0, stream>>>(pO, pm, pl, mask, xsb);
  k_out<<<256, 512, 0, stream>>>(xsb, wt, bo, xs, yout);
  k_ln<<<M_, 256, 0, stream>>>(yout, gamma, beta);
}